// Round 1
// baseline (495.928 us; speedup 1.0000x reference)
//
#include <hip/hip_runtime.h>
#include <stdint.h>
#include <stddef.h>

// ==== JAX threefry mode: 1 = jax_threefry_partitionable (default in modern JAX),
// ====                    0 = legacy "original" iota-split mode.
#define JAX_PARTITIONABLE 1

#define B_   256
#define N_   512
#define NP_  513     // N+1
#define KD_  32
#define T_   64
#define NEGC 1e9f

// ---------------- threefry2x32 (matches jax/_src/prng.py) ----------------
__host__ __device__ __forceinline__ void tf2x32(uint32_t k0, uint32_t k1,
    uint32_t x0, uint32_t x1, uint32_t& o0, uint32_t& o1) {
  const uint32_t k2 = k0 ^ k1 ^ 0x1BD11BDAu;
#define TFR(r) { x0 += x1; x1 = (x1 << (r)) | (x1 >> (32 - (r))); x1 ^= x0; }
  x0 += k0; x1 += k1;
  TFR(13) TFR(15) TFR(26) TFR(6)
  x0 += k1; x1 += k2 + 1u;
  TFR(17) TFR(29) TFR(16) TFR(24)
  x0 += k2; x1 += k0 + 2u;
  TFR(13) TFR(15) TFR(26) TFR(6)
  x0 += k0; x1 += k1 + 3u;
  TFR(17) TFR(29) TFR(16) TFR(24)
  x0 += k1; x1 += k2 + 4u;
  TFR(13) TFR(15) TFR(26) TFR(6)
  x0 += k2; x1 += k0 + 5u;
#undef TFR
  o0 = x0; o1 = x1;
}

struct SkKeys { uint32_t k[128]; };  // sk_t = (k[2t], k[2t+1]) for t=0..63

// Host-side: the rng chain is seed-42-deterministic and input-independent.
static SkKeys compute_chain() {
  SkKeys s;
  uint32_t r0 = 0u, r1 = 42u;   // jax.random.key(42) -> (hi, lo) = (0, 42)
  for (int t = 0; t < 64; ++t) {
#if JAX_PARTITIONABLE
    // split: counts (hi,lo) = (0,0) -> new rng ; (0,1) -> subkey
    uint32_t a0, a1, b0, b1;
    tf2x32(r0, r1, 0u, 0u, a0, a1);
    tf2x32(r0, r1, 0u, 1u, b0, b1);
    s.k[2*t] = b0; s.k[2*t+1] = b1;
    r0 = a0; r1 = a1;
#else
    // original split: counts [0,1,2,3] -> pairs (0,2),(1,3);
    // rng' = (lane0(0,2), lane0(1,3)), sk = (lane1(0,2), lane1(1,3))
    uint32_t p0, p1, q0, q1;
    tf2x32(r0, r1, 0u, 2u, p0, p1);
    tf2x32(r0, r1, 1u, 3u, q0, q1);
    s.k[2*t] = p1; s.k[2*t+1] = q1;
    r0 = p0; r1 = q0;
#endif
  }
  return s;
}

__device__ __forceinline__ float gumbel_draw(uint32_t k0, uint32_t k1, int b, int n) {
  uint32_t bits;
#if JAX_PARTITIONABLE
  uint32_t j = (uint32_t)(b * NP_ + n);
  uint32_t o0, o1; tf2x32(k0, k1, 0u, j, o0, o1);
  bits = o0 ^ o1;
#else
  int j = b * NP_ + n;                 // 131328 elements, half = 65664
  uint32_t o0, o1;
  if (j < 65664) { tf2x32(k0, k1, (uint32_t)j, (uint32_t)(j + 65664), o0, o1); bits = o0; }
  else           { tf2x32(k0, k1, (uint32_t)(j - 65664), (uint32_t)j, o0, o1); bits = o1; }
#endif
  // uniform(minval=tiny, maxval=1): bitcast trick, then f*1.0f + tiny, clamped
  float f = __uint_as_float((bits >> 9) | 0x3F800000u) - 1.0f;
  const float TINY = 1.17549435e-38f;
  float u = fmaxf(TINY, f + TINY);
  return -logf(-logf(u));
}

__device__ __forceinline__ float sigm(float x) {
  // XLA logistic expansion: 0.5 + 0.5*tanh(0.5x)
  return 0.5f + 0.5f * tanhf(0.5f * x);
}

// ---------------- LDS layout (float indices) ----------------
// key_s stored transposed: key_s[c][n] at KEY + c*513 + n  (conflict-free dots)
#define OFF_KEY   0        // 32*513 = 16416
#define OFF_WB    16416    // 8192: phase A = key_fc_w[256][32]; scan = wx[32][128] | wh[32][128]
#define OFF_ENT   24608    // 4096: 16x256 entity staging
#define OFF_MASK  28704    // 513
#define OFF_UNITS 29217    // 513
#define OFF_TA    29730    // 256
#define OFF_TB    29986    // 256
#define OFF_GX    30242    // 128
#define OFF_GH    30370    // 128
#define OFF_GATE  30498    // 128
#define OFF_XS    30626    // 32
#define OFF_HS    30658    // 32
#define OFF_CS    30690    // 32
#define OFF_LNP   30722    // 640: gx_g,gx_b,gh_g,gh_b,lstm_b (128 each)
#define OFF_ES    31362    // 32
#define OFF_PART  31394    // 16*32
#define OFF_RV    31906    // 8
#define OFF_RI    31914    // 8 (ints, aliased)
#define OFF_STT   31922    // 4: m_x, rstd_x, m_h, rstd_h
#define OFF_FLG   31926    // 1 (int, aliased): done
#define LDS_FLOATS 31928

__global__ void __launch_bounds__(512)
suh_kernel(const float* __restrict__ emb, const float* __restrict__ autm,
           const float* __restrict__ aum, const float* __restrict__ ent,
           const float* __restrict__ temp_p,
           const float* __restrict__ key_w, const float* __restrict__ key_b,
           const float* __restrict__ func_w, const float* __restrict__ func_b,
           const float* __restrict__ fc1_w, const float* __restrict__ fc1_b,
           const float* __restrict__ fc2_w, const float* __restrict__ fc2_b,
           const float* __restrict__ emb_w, const float* __restrict__ emb_b,
           const float* __restrict__ wx, const float* __restrict__ wh,
           const float* __restrict__ lstm_bb,
           const float* __restrict__ ln_gx, const float* __restrict__ ln_bx,
           const float* __restrict__ ln_gh, const float* __restrict__ ln_bh,
           float* __restrict__ out_logits, float* __restrict__ out_valid,
           float* __restrict__ out_units, float* __restrict__ out_final,
           SkKeys sk)
{
  extern __shared__ float sm[];
  int* smi = (int*)sm;
  const int b   = blockIdx.x;
  const int tid = threadIdx.x;
  const int c   = tid & 31;

  // ---------- phase A: key[b] = ent[b] @ key_fc_w + key_fc_b  -> LDS (transposed) ----------
  for (int i = tid; i < 256 * 32; i += 512) sm[OFF_WB + i] = key_w[i];
  __syncthreads();
  {
    const int r = tid >> 5;                       // 0..15
    for (int tile = 0; tile < 32; ++tile) {
      const float* eb = ent + ((size_t)b * N_ + tile * 16) * 256;
      for (int i = tid; i < 16 * 256; i += 512) sm[OFF_ENT + i] = eb[i];
      __syncthreads();
      float acc = 0.f;
      const float* er = &sm[OFF_ENT + r * 256];
      #pragma unroll 4
      for (int k = 0; k < 256; ++k) acc += er[k] * sm[OFF_WB + k * 32 + c];
      sm[OFF_KEY + c * NP_ + tile * 16 + r] = acc + key_b[c];
      __syncthreads();
    }
  }
  if (tid < 32) sm[OFF_KEY + tid * NP_ + N_] = 0.f;   // appended zero key row

  // ---------- phase B: x0 = relu((relu(emb@fc1+b1) + relu(autm@fw+fb)) @ fc2 + b2) ----------
  if (tid < 256) {
    float a = 0.f;
    const float* e = emb + (size_t)b * 1024;
    #pragma unroll 8
    for (int k = 0; k < 1024; ++k) a += e[k] * fc1_w[k * 256 + tid];
    sm[OFF_TA + tid] = fmaxf(a + fc1_b[tid], 0.f);
  } else {
    const int j = tid - 256;
    float a = 0.f;
    const float* m = autm + (size_t)b * 259;
    for (int k = 0; k < 259; ++k) a += m[k] * func_w[k * 256 + j];
    sm[OFF_TB + j] = fmaxf(a + func_b[j], 0.f);
  }
  __syncthreads();
  if (tid < 256) sm[OFF_TA + tid] = sm[OFF_TA + tid] + sm[OFF_TB + tid];
  __syncthreads();
  if (tid < 32) {
    float a = 0.f;
    #pragma unroll 8
    for (int j = 0; j < 256; ++j) a += sm[OFF_TA + j] * fc2_w[j * 32 + tid];
    a = fmaxf(a + fc2_b[tid], 0.f);
    sm[OFF_XS + tid] = a;
    sm[OFF_HS + tid] = 0.f;
    sm[OFF_CS + tid] = 0.f;
  }

  // ---------- phase C: stage LSTM weights/params, init mask/units/done ----------
  for (int i = tid; i < 4096; i += 512) sm[OFF_WB + i]        = wx[i];
  for (int i = tid; i < 4096; i += 512) sm[OFF_WB + 4096 + i] = wh[i];
  if (tid < 128) {
    sm[OFF_LNP + tid]        = ln_gx[tid];
    sm[OFF_LNP + 128 + tid]  = ln_bx[tid];
    sm[OFF_LNP + 256 + tid]  = ln_gh[tid];
    sm[OFF_LNP + 384 + tid]  = ln_bh[tid];
    sm[OFF_LNP + 512 + tid]  = lstm_bb[tid];
  }
  {
    const float* am = aum + (size_t)b * N_;
    for (int n = tid; n < NP_; n += 512) {
      sm[OFF_MASK + n]  = (n < N_) ? am[n] : 1.0f;
      sm[OFF_UNITS + n] = 0.f;
    }
  }
  if (tid == 0) smi[OFF_FLG] = 0;
  __syncthreads();

  const float temp = temp_p[0];

  // ---------- phase D: 64-step scan ----------
  for (int t = 0; t < T_; ++t) {
    // LN-LSTM gates: gx = x@wx, gh = h@wh
    if (tid < 128) {
      float a = 0.f;
      #pragma unroll
      for (int k = 0; k < 32; ++k) a += sm[OFF_XS + k] * sm[OFF_WB + k * 128 + tid];
      sm[OFF_GX + tid] = a;
    } else if (tid < 256) {
      const int j = tid - 128;
      float a = 0.f;
      #pragma unroll
      for (int k = 0; k < 32; ++k) a += sm[OFF_HS + k] * sm[OFF_WB + 4096 + k * 128 + j];
      sm[OFF_GH + j] = a;
    }
    __syncthreads();
    // LN stats: wave 0 -> gx, wave 1 -> gh  (mean, then mean((x-m)^2), per reference)
    if (tid < 128) {
      const int w = tid >> 6, lane = tid & 63;
      const int base = w ? OFF_GH : OFF_GX;
      float v1 = sm[base + lane], v2 = sm[base + 64 + lane];
      float s = v1 + v2;
      for (int off = 32; off; off >>= 1) s += __shfl_down(s, off);
      float m = __shfl(s, 0) * (1.0f / 128.0f);
      float d1 = v1 - m, d2 = v2 - m;
      float ss = d1 * d1 + d2 * d2;
      for (int off = 32; off; off >>= 1) ss += __shfl_down(ss, off);
      float var = __shfl(ss, 0) * (1.0f / 128.0f);
      if (lane == 0) {
        sm[OFF_STT + 2 * w]     = m;
        sm[OFF_STT + 2 * w + 1] = 1.0f / sqrtf(var + 1e-5f);
      }
    }
    __syncthreads();
    if (tid < 128) {
      float mx = sm[OFF_STT], ix = sm[OFF_STT + 1], mh = sm[OFF_STT + 2], ih = sm[OFF_STT + 3];
      float a = (sm[OFF_GX + tid] - mx) * ix * sm[OFF_LNP + tid]       + sm[OFF_LNP + 128 + tid];
      float h = (sm[OFF_GH + tid] - mh) * ih * sm[OFF_LNP + 256 + tid] + sm[OFF_LNP + 384 + tid];
      sm[OFF_GATE + tid] = a + h + sm[OFF_LNP + 512 + tid];
    }
    __syncthreads();
    if (tid < 32) {
      float ig = sm[OFF_GATE + tid],      fg = sm[OFF_GATE + 32 + tid];
      float og = sm[OFF_GATE + 64 + tid], ug = sm[OFF_GATE + 96 + tid];
      float cN = sigm(fg) * sm[OFF_CS + tid] + sigm(ig) * tanhf(ug);
      float hN = sigm(og) * tanhf(cN);
      sm[OFF_CS + tid] = cN; sm[OFF_HS + tid] = hN; sm[OFF_XS + tid] = hN;
    }
    __syncthreads();

    // pointer scores q + gumbel + argmax
    const uint32_t kk0 = sk.k[2 * t], kk1 = sk.k[2 * t + 1];
    float bv = -__builtin_inff(); int bi = 0;
    float* lrow = out_logits + ((size_t)t * B_ + b) * NP_;
    for (int n = tid; n < NP_; n += 512) {
      float a = 0.f;
      #pragma unroll
      for (int k = 0; k < 32; ++k) a += sm[OFF_HS + k] * sm[OFF_KEY + k * NP_ + n];
      float q = a * (1.0f / 32.0f);
      q = q - (1.0f - sm[OFF_MASK + n]) * NEGC;
      lrow[n] = q;
      float v = q / temp + gumbel_draw(kk0, kk1, b, n);
      if (v > bv || (v == bv && n < bi)) { bv = v; bi = n; }
    }
    for (int off = 32; off; off >>= 1) {
      float ov = __shfl_down(bv, off);
      int   oi = __shfl_down(bi, off);
      if (ov > bv || (ov == bv && oi < bi)) { bv = ov; bi = oi; }
    }
    if ((tid & 63) == 0) { sm[OFF_RV + (tid >> 6)] = bv; smi[OFF_RI + (tid >> 6)] = bi; }
    __syncthreads();
    if (tid == 0) {
      bv = sm[OFF_RV]; bi = smi[OFF_RI];
      for (int w = 1; w < 8; ++w) {
        float ov = sm[OFF_RV + w]; int oi = smi[OFF_RI + w];
        if (ov > bv || (ov == bv && oi < bi)) { bv = ov; bi = oi; }
      }
      const int done   = smi[OFF_FLG];
      const int active = !done;
      const int is_end = (bi == N_);
      out_valid[(size_t)t * B_ + b] = active ? 1.0f : 0.0f;
      if (active && !is_end) { sm[OFF_UNITS + bi] = 1.0f; sm[OFF_MASK + bi] = 0.0f; }
      if (active && is_end) smi[OFF_FLG] = 1;
    }
    __syncthreads();
  }

  // ---------- phase E: emb_sel = (units . key)/513 ; final = emb + emb_sel@W + b ----------
  {
    const int g = tid >> 5;       // 0..15
    float p = 0.f;
    const int n0 = g * 32;
    for (int nn = 0; nn < 32; ++nn) {
      const int n = n0 + nn;
      p += sm[OFF_UNITS + n] * sm[OFF_KEY + c * NP_ + n];
    }
    if (g == 15) p += sm[OFF_UNITS + N_] * sm[OFF_KEY + c * NP_ + N_];
    sm[OFF_PART + g * 32 + c] = p;
  }
  for (int n = tid; n < NP_; n += 512) out_units[(size_t)b * NP_ + n] = sm[OFF_UNITS + n];
  __syncthreads();
  if (tid < 32) {
    float s = 0.f;
    #pragma unroll
    for (int g = 0; g < 16; ++g) s += sm[OFF_PART + g * 32 + tid];
    sm[OFF_ES + tid] = s / 513.0f;
  }
  __syncthreads();
  {
    const float* e = emb + (size_t)b * 1024;
    for (int d = tid; d < 1024; d += 512) {
      float a = 0.f;
      #pragma unroll
      for (int k = 0; k < 32; ++k) a += sm[OFF_ES + k] * emb_w[k * 1024 + d];
      out_final[(size_t)b * 1024 + d] = e[d] + a + emb_b[d];
    }
  }
}

extern "C" void kernel_launch(void* const* d_in, const int* in_sizes, int n_in,
                              void* d_out, int out_size, void* d_ws, size_t ws_size,
                              hipStream_t stream) {
  (void)in_sizes; (void)n_in; (void)d_ws; (void)ws_size; (void)out_size;
  const float* emb    = (const float*)d_in[0];
  const float* autm   = (const float*)d_in[1];
  const float* aum    = (const float*)d_in[2];
  const float* ent    = (const float*)d_in[3];
  const float* temp   = (const float*)d_in[4];
  const float* key_w  = (const float*)d_in[5];
  const float* key_b  = (const float*)d_in[6];
  const float* func_w = (const float*)d_in[7];
  const float* func_b = (const float*)d_in[8];
  const float* fc1_w  = (const float*)d_in[9];
  const float* fc1_b  = (const float*)d_in[10];
  const float* fc2_w  = (const float*)d_in[11];
  const float* fc2_b  = (const float*)d_in[12];
  const float* emb_w  = (const float*)d_in[13];
  const float* emb_b  = (const float*)d_in[14];
  const float* wx     = (const float*)d_in[15];
  const float* wh     = (const float*)d_in[16];
  const float* lb     = (const float*)d_in[17];
  const float* gxg    = (const float*)d_in[18];
  const float* gxb    = (const float*)d_in[19];
  const float* ghg    = (const float*)d_in[20];
  const float* ghb    = (const float*)d_in[21];
  float* out = (float*)d_out;

  // output layout: logits[64,256,513] | valid[64,256] | units[256,513] | final[256,1024]
  const size_t OFF_V = (size_t)T_ * B_ * NP_;          // 8,404,992
  const size_t OFF_U = OFF_V + (size_t)T_ * B_;        // 8,421,376
  const size_t OFF_F = OFF_U + (size_t)B_ * NP_;       // 8,552,704

  SkKeys sk = compute_chain();   // deterministic (seed 42), graph-capture safe

  suh_kernel<<<dim3(B_), dim3(512), LDS_FLOATS * sizeof(float), stream>>>(
      emb, autm, aum, ent, temp, key_w, key_b, func_w, func_b,
      fc1_w, fc1_b, fc2_w, fc2_b, emb_w, emb_b,
      wx, wh, lb, gxg, gxb, ghg, ghb,
      out, out + OFF_V, out + OFF_U, out + OFF_F, sk);
}

// Round 2
// 412.918 us; speedup vs baseline: 1.2010x; 1.2010x over previous
//
#include <hip/hip_runtime.h>
#include <stdint.h>
#include <stddef.h>

// ==== JAX threefry mode: 1 = jax_threefry_partitionable (default in modern JAX)
#define JAX_PARTITIONABLE 1

#define B_   256
#define N_   512
#define NP_  513     // N+1
#define T_   64
#define NEGC 1e9f

// ---------------- threefry2x32 (matches jax/_src/prng.py) ----------------
__host__ __device__ __forceinline__ void tf2x32(uint32_t k0, uint32_t k1,
    uint32_t x0, uint32_t x1, uint32_t& o0, uint32_t& o1) {
  const uint32_t k2 = k0 ^ k1 ^ 0x1BD11BDAu;
#define TFR(r) { x0 += x1; x1 = (x1 << (r)) | (x1 >> (32 - (r))); x1 ^= x0; }
  x0 += k0; x1 += k1;
  TFR(13) TFR(15) TFR(26) TFR(6)
  x0 += k1; x1 += k2 + 1u;
  TFR(17) TFR(29) TFR(16) TFR(24)
  x0 += k2; x1 += k0 + 2u;
  TFR(13) TFR(15) TFR(26) TFR(6)
  x0 += k0; x1 += k1 + 3u;
  TFR(17) TFR(29) TFR(16) TFR(24)
  x0 += k1; x1 += k2 + 4u;
  TFR(13) TFR(15) TFR(26) TFR(6)
  x0 += k2; x1 += k0 + 5u;
#undef TFR
  o0 = x0; o1 = x1;
}

struct SkKeys { uint32_t k[128]; };  // sk_t = (k[2t], k[2t+1])

static SkKeys compute_chain() {
  SkKeys s;
  uint32_t r0 = 0u, r1 = 42u;   // jax.random.key(42)
  for (int t = 0; t < 64; ++t) {
#if JAX_PARTITIONABLE
    uint32_t a0, a1, b0, b1;
    tf2x32(r0, r1, 0u, 0u, a0, a1);
    tf2x32(r0, r1, 0u, 1u, b0, b1);
    s.k[2*t] = b0; s.k[2*t+1] = b1;
    r0 = a0; r1 = a1;
#else
    uint32_t p0, p1, q0, q1;
    tf2x32(r0, r1, 0u, 2u, p0, p1);
    tf2x32(r0, r1, 1u, 3u, q0, q1);
    s.k[2*t] = p1; s.k[2*t+1] = q1;
    r0 = p0; r1 = q0;
#endif
  }
  return s;
}

__device__ __forceinline__ float gumbel_draw(uint32_t k0, uint32_t k1, int b, int n) {
  uint32_t bits;
#if JAX_PARTITIONABLE
  uint32_t j = (uint32_t)(b * NP_ + n);
  uint32_t o0, o1; tf2x32(k0, k1, 0u, j, o0, o1);
  bits = o0 ^ o1;
#else
  int j = b * NP_ + n;
  uint32_t o0, o1;
  if (j < 65664) { tf2x32(k0, k1, (uint32_t)j, (uint32_t)(j + 65664), o0, o1); bits = o0; }
  else           { tf2x32(k0, k1, (uint32_t)(j - 65664), (uint32_t)j, o0, o1); bits = o1; }
#endif
  float f = __uint_as_float((bits >> 9) | 0x3F800000u) - 1.0f;
  const float TINY = 1.17549435e-38f;
  float u = fmaxf(TINY, f + TINY);
  return -logf(-logf(u));
}

__device__ __forceinline__ float sigm(float x) {
  return 0.5f + 0.5f * tanhf(0.5f * x);   // XLA logistic
}

// ---------------- workspace layout (floats) ----------------
#define WS_KEY 0                      // [B][32][513] c-major, n<512 written
#define WS_X0  (B_ * 32 * NP_)        // 4,202,496 : [B][32]

// =============== kernel 1: key GEMM (blocks 0..1023) + x0 MLP (1024..1279) ===============
__global__ void __launch_bounds__(256)
pre_kernel(const float* __restrict__ ent, const float* __restrict__ key_w,
           const float* __restrict__ key_b,
           const float* __restrict__ emb, const float* __restrict__ fc1_w,
           const float* __restrict__ fc1_b,
           const float* __restrict__ autm, const float* __restrict__ func_w,
           const float* __restrict__ func_b,
           const float* __restrict__ fc2_w, const float* __restrict__ fc2_b,
           float* __restrict__ ws)
{
  __shared__ __align__(16) float smAll[16384];   // 64 KB: A^T[64][128] | W[256][32]
  const int tid = threadIdx.x;

  if (blockIdx.x < 1024) {
    // ---- tall-skinny GEMM: 128 rows x 32 cols, K=256 in 4 chunks of 64 ----
    float* smA = smAll;            // [64][128] k-major
    float* smW = smAll + 8192;     // [256][32]
    const int blk = blockIdx.x;
    const int R0  = blk * 128;             // flattened row base (b*512 + n)
    const int b   = R0 >> 9;
    const int nb  = R0 & 511;
    const int rg  = tid >> 3;              // 0..31 -> rows rg*4..+3
    const int cg  = tid & 7;               // 0..7  -> cols cg*4..+3

    // stage key_w once
    for (int i = tid; i < 2048; i += 256)
      ((float4*)smW)[i] = ((const float4*)key_w)[i];

    float acc[4][4];
    #pragma unroll
    for (int i = 0; i < 4; ++i)
      #pragma unroll
      for (int j = 0; j < 4; ++j) acc[i][j] = 0.f;

    const int row  = tid >> 1;             // 0..127 (staging role)
    const int half = tid & 1;

    for (int kc = 0; kc < 4; ++kc) {
      // stage A^T chunk: smA[kl][row] = ent[R0+row][kc*64+kl]
      const float4* src = (const float4*)(ent + ((size_t)(R0 + row)) * 256 + kc * 64 + half * 32);
      float4 vv[8];
      #pragma unroll
      for (int r = 0; r < 8; ++r) vv[r] = src[r];
      #pragma unroll
      for (int r = 0; r < 8; ++r) {
        const int kl = half * 32 + r * 4;
        smA[(kl + 0) * 128 + row] = vv[r].x;
        smA[(kl + 1) * 128 + row] = vv[r].y;
        smA[(kl + 2) * 128 + row] = vv[r].z;
        smA[(kl + 3) * 128 + row] = vv[r].w;
      }
      __syncthreads();
      #pragma unroll 4
      for (int k = 0; k < 64; ++k) {
        float4 av = *(const float4*)&smA[k * 128 + rg * 4];
        float4 bv = *(const float4*)&smW[(kc * 64 + k) * 32 + cg * 4];
        float ar[4] = {av.x, av.y, av.z, av.w};
        float br[4] = {bv.x, bv.y, bv.z, bv.w};
        #pragma unroll
        for (int i = 0; i < 4; ++i)
          #pragma unroll
          for (int j = 0; j < 4; ++j) acc[i][j] += ar[i] * br[j];
      }
      __syncthreads();
    }
    float4 bb = *(const float4*)&key_b[cg * 4];
    float bbr[4] = {bb.x, bb.y, bb.z, bb.w};
    #pragma unroll
    for (int j = 0; j < 4; ++j) {
      const int c = cg * 4 + j;
      float* dst = ws + WS_KEY + ((size_t)(b * 32 + c)) * NP_ + nb + rg * 4;
      #pragma unroll
      for (int i = 0; i < 4; ++i) dst[i] = acc[i][j] + bbr[j];
    }
  } else {
    // ---- x0 MLP: one block per batch row ----
    float* smX = smAll;
    const int b = blockIdx.x - 1024;
    const int j = tid;
    {
      float a = 0.f;
      const float* e = emb + (size_t)b * 1024;
      #pragma unroll 8
      for (int k = 0; k < 1024; ++k) a += e[k] * fc1_w[k * 256 + j];
      a = fmaxf(a + fc1_b[j], 0.f);
      float f = 0.f;
      const float* m = autm + (size_t)b * 259;
      for (int k = 0; k < 259; ++k) f += m[k] * func_w[k * 256 + j];
      f = fmaxf(f + func_b[j], 0.f);
      smX[j] = a + f;
    }
    __syncthreads();
    if (j < 32) {
      float s = 0.f;
      #pragma unroll 8
      for (int m = 0; m < 256; ++m) s += smX[m] * fc2_w[m * 32 + j];
      ws[WS_X0 + b * 32 + j] = fmaxf(s + fc2_b[j], 0.f);
    }
  }
}

// =============== kernel 2: scan ===============
// LDS layout (floats)
#define OFF_KEY   0        // 32*513 = 16416, c-major [32][513]
#define OFF_WB    16416    // 8192: wx[32][128] | wh[32][128]
#define OFF_MASK  24608    // 513
#define OFF_UNITS 25124    // 513
#define OFF_GUM   25640    // 513
#define OFF_GX    26156    // 128
#define OFF_GH    26284    // 128
#define OFF_STT   26412    // 4
#define OFF_XS    26416    // 32
#define OFF_HS    26448    // 32
#define OFF_CS    26480    // 32
#define OFF_LNP   26512    // 640
#define OFF_ES    27152    // 32
#define OFF_PART  27184    // 512
#define OFF_RV    27696    // 8
#define OFF_RI    27704    // 8 (ints aliased)
#define OFF_FLG   27712    // 1 (int aliased)
#define LDS_FLOATS 27716

__global__ void __launch_bounds__(512)
suh_kernel(const float* __restrict__ ws_key_x0,
           const float* __restrict__ aum, const float* __restrict__ temp_p,
           const float* __restrict__ emb,
           const float* __restrict__ emb_w, const float* __restrict__ emb_b,
           const float* __restrict__ wx, const float* __restrict__ wh,
           const float* __restrict__ lstm_bb,
           const float* __restrict__ ln_gx, const float* __restrict__ ln_bx,
           const float* __restrict__ ln_gh, const float* __restrict__ ln_bh,
           float* __restrict__ out_logits, float* __restrict__ out_valid,
           float* __restrict__ out_units, float* __restrict__ out_final,
           SkKeys sk)
{
  extern __shared__ __align__(16) float sm[];
  int* smi = (int*)sm;
  const int b   = blockIdx.x;
  const int tid = threadIdx.x;

  // ---------- prologue: load key (c-major), weights, params, state ----------
  {
    const float4* kv = (const float4*)(ws_key_x0 + WS_KEY + (size_t)b * (32 * NP_));
    for (int i = tid; i < (32 * NP_) / 4; i += 512) ((float4*)sm)[i] = kv[i];  // 16416/4=4104... see note
  }
  // 16416 % 4 == 0 -> 4104 vec4s covers all
  for (int i = tid; i < 4096; i += 512) sm[OFF_WB + i]        = wx[i];
  for (int i = tid; i < 4096; i += 512) sm[OFF_WB + 4096 + i] = wh[i];
  if (tid < 128) {
    sm[OFF_LNP + tid]       = ln_gx[tid];
    sm[OFF_LNP + 128 + tid] = ln_bx[tid];
    sm[OFF_LNP + 256 + tid] = ln_gh[tid];
    sm[OFF_LNP + 384 + tid] = ln_bh[tid];
    sm[OFF_LNP + 512 + tid] = lstm_bb[tid];
  }
  {
    const float* am = aum + (size_t)b * N_;
    for (int n = tid; n < NP_; n += 512) {
      sm[OFF_MASK + n]  = (n < N_) ? am[n] : 1.0f;
      sm[OFF_UNITS + n] = 0.f;
    }
  }
  if (tid < 32) {
    sm[OFF_XS + tid] = ws_key_x0[WS_X0 + b * 32 + tid];
    sm[OFF_HS + tid] = 0.f;
    sm[OFF_CS + tid] = 0.f;
  }
  if (tid == 0) smi[OFF_FLG] = 0;
  __syncthreads();
  if (tid < 32) sm[OFF_KEY + tid * NP_ + N_] = 0.f;   // appended zero key row
  __syncthreads();

  const float temp = temp_p[0];

  // ---------- 64-step scan (5 barriers/step) ----------
  for (int t = 0; t < T_; ++t) {
    const uint32_t kk0 = sk.k[2 * t], kk1 = sk.k[2 * t + 1];
    // R0: gate GEMMs on waves 0-3; gumbel on waves 4-7
    if (tid < 128) {
      float a = 0.f;
      #pragma unroll
      for (int k = 0; k < 32; ++k) a += sm[OFF_XS + k] * sm[OFF_WB + k * 128 + tid];
      sm[OFF_GX + tid] = a;
    } else if (tid < 256) {
      const int j = tid - 128;
      float a = 0.f;
      #pragma unroll
      for (int k = 0; k < 32; ++k) a += sm[OFF_HS + k] * sm[OFF_WB + 4096 + k * 128 + j];
      sm[OFF_GH + j] = a;
    } else {
      const int t2 = tid - 256;
      sm[OFF_GUM + t2]       = gumbel_draw(kk0, kk1, b, t2);
      sm[OFF_GUM + t2 + 256] = gumbel_draw(kk0, kk1, b, t2 + 256);
      if (t2 == 0) sm[OFF_GUM + 512] = gumbel_draw(kk0, kk1, b, 512);
    }
    __syncthreads();                                    // bar1
    // LN stats (2 waves): identical arithmetic to the passing version
    if (tid < 128) {
      const int w = tid >> 6, lane = tid & 63;
      const int base = w ? OFF_GH : OFF_GX;
      float v1 = sm[base + lane], v2 = sm[base + 64 + lane];
      float s = v1 + v2;
      for (int off = 32; off; off >>= 1) s += __shfl_down(s, off);
      float m = __shfl(s, 0) * (1.0f / 128.0f);
      float d1 = v1 - m, d2 = v2 - m;
      float ss = d1 * d1 + d2 * d2;
      for (int off = 32; off; off >>= 1) ss += __shfl_down(ss, off);
      float var = __shfl(ss, 0) * (1.0f / 128.0f);
      if (lane == 0) {
        sm[OFF_STT + 2 * w]     = m;
        sm[OFF_STT + 2 * w + 1] = 1.0f / sqrtf(var + 1e-5f);
      }
    }
    __syncthreads();                                    // bar2
    // gates + cell fused on 32 threads (thread c owns all 4 quarters)
    if (tid < 32) {
      const float mx = sm[OFF_STT],     ix = sm[OFF_STT + 1];
      const float mh = sm[OFF_STT + 2], ih = sm[OFF_STT + 3];
      float g[4];
      #pragma unroll
      for (int qd = 0; qd < 4; ++qd) {
        const int j = tid + qd * 32;
        float a = (sm[OFF_GX + j] - mx) * ix * sm[OFF_LNP + j]       + sm[OFF_LNP + 128 + j];
        float h = (sm[OFF_GH + j] - mh) * ih * sm[OFF_LNP + 256 + j] + sm[OFF_LNP + 384 + j];
        g[qd] = a + h + sm[OFF_LNP + 512 + j];
      }
      float cN = sigm(g[1]) * sm[OFF_CS + tid] + sigm(g[0]) * tanhf(g[3]);
      float hN = sigm(g[2]) * tanhf(cN);
      sm[OFF_CS + tid] = cN; sm[OFF_HS + tid] = hN; sm[OFF_XS + tid] = hN;
    }
    __syncthreads();                                    // bar3
    // pointer scores + argmax partials (all 512 threads)
    float4 h4[8];
    #pragma unroll
    for (int r = 0; r < 8; ++r) h4[r] = *(const float4*)&sm[OFF_HS + r * 4];
    float hr[32] = {h4[0].x,h4[0].y,h4[0].z,h4[0].w, h4[1].x,h4[1].y,h4[1].z,h4[1].w,
                    h4[2].x,h4[2].y,h4[2].z,h4[2].w, h4[3].x,h4[3].y,h4[3].z,h4[3].w,
                    h4[4].x,h4[4].y,h4[4].z,h4[4].w, h4[5].x,h4[5].y,h4[5].z,h4[5].w,
                    h4[6].x,h4[6].y,h4[6].z,h4[6].w, h4[7].x,h4[7].y,h4[7].z,h4[7].w};
    float bv = -__builtin_inff(); int bi = 0;
    float* lrow = out_logits + ((size_t)t * B_ + b) * NP_;
    for (int n = tid; n < NP_; n += 512) {
      float a = 0.f;
      #pragma unroll
      for (int k = 0; k < 32; ++k) a += hr[k] * sm[OFF_KEY + k * NP_ + n];
      float q = a * (1.0f / 32.0f);
      q = q - (1.0f - sm[OFF_MASK + n]) * NEGC;
      lrow[n] = q;
      float v = q / temp + sm[OFF_GUM + n];
      if (v > bv || (v == bv && n < bi)) { bv = v; bi = n; }
    }
    for (int off = 32; off; off >>= 1) {
      float ov = __shfl_down(bv, off);
      int   oi = __shfl_down(bi, off);
      if (ov > bv || (ov == bv && oi < bi)) { bv = ov; bi = oi; }
    }
    if ((tid & 63) == 0) { sm[OFF_RV + (tid >> 6)] = bv; smi[OFF_RI + (tid >> 6)] = bi; }
    __syncthreads();                                    // bar4
    // final reduce on wave 0 (all 64 lanes active for defined shuffles)
    if (tid < 64) {
      float v = (tid < 8) ? sm[OFF_RV + tid] : -__builtin_inff();
      int   i = (tid < 8) ? smi[OFF_RI + tid] : 0x7fffffff;
      #pragma unroll
      for (int off = 4; off; off >>= 1) {
        float ov = __shfl_down(v, off);
        int   oi = __shfl_down(i, off);
        if (ov > v || (ov == v && oi < i)) { v = ov; i = oi; }
      }
      if (tid == 0) {
        const int done   = smi[OFF_FLG];
        const int active = !done;
        const int is_end = (i == N_);
        out_valid[(size_t)t * B_ + b] = active ? 1.0f : 0.0f;
        if (active && !is_end) { sm[OFF_UNITS + i] = 1.0f; sm[OFF_MASK + i] = 0.0f; }
        if (active && is_end) smi[OFF_FLG] = 1;
      }
    }
    __syncthreads();                                    // bar5
  }

  // ---------- epilogue: emb_sel & final ----------
  {
    const int g = tid >> 5, c = tid & 31;
    float p = 0.f;
    const int n0 = g * 32;
    for (int nn = 0; nn < 32; ++nn) {
      const int n = n0 + nn;
      p += sm[OFF_UNITS + n] * sm[OFF_KEY + c * NP_ + n];
    }
    if (g == 15) p += sm[OFF_UNITS + N_] * sm[OFF_KEY + c * NP_ + N_];
    sm[OFF_PART + g * 32 + c] = p;
  }
  for (int n = tid; n < NP_; n += 512) out_units[(size_t)b * NP_ + n] = sm[OFF_UNITS + n];
  __syncthreads();
  if (tid < 32) {
    float s = 0.f;
    #pragma unroll
    for (int g = 0; g < 16; ++g) s += sm[OFF_PART + g * 32 + tid];
    sm[OFF_ES + tid] = s / 513.0f;
  }
  __syncthreads();
  {
    const float* e = emb + (size_t)b * 1024;
    for (int d = tid; d < 1024; d += 512) {
      float a = 0.f;
      #pragma unroll
      for (int k = 0; k < 32; ++k) a += sm[OFF_ES + k] * emb_w[k * 1024 + d];
      out_final[(size_t)b * 1024 + d] = e[d] + a + emb_b[d];
    }
  }
}

extern "C" void kernel_launch(void* const* d_in, const int* in_sizes, int n_in,
                              void* d_out, int out_size, void* d_ws, size_t ws_size,
                              hipStream_t stream) {
  (void)in_sizes; (void)n_in; (void)ws_size; (void)out_size;
  const float* emb    = (const float*)d_in[0];
  const float* autm   = (const float*)d_in[1];
  const float* aum    = (const float*)d_in[2];
  const float* ent    = (const float*)d_in[3];
  const float* temp   = (const float*)d_in[4];
  const float* key_w  = (const float*)d_in[5];
  const float* key_b  = (const float*)d_in[6];
  const float* func_w = (const float*)d_in[7];
  const float* func_b = (const float*)d_in[8];
  const float* fc1_w  = (const float*)d_in[9];
  const float* fc1_b  = (const float*)d_in[10];
  const float* fc2_w  = (const float*)d_in[11];
  const float* fc2_b  = (const float*)d_in[12];
  const float* emb_w  = (const float*)d_in[13];
  const float* emb_b  = (const float*)d_in[14];
  const float* wx     = (const float*)d_in[15];
  const float* wh     = (const float*)d_in[16];
  const float* lb     = (const float*)d_in[17];
  const float* gxg    = (const float*)d_in[18];
  const float* gxb    = (const float*)d_in[19];
  const float* ghg    = (const float*)d_in[20];
  const float* ghb    = (const float*)d_in[21];
  float* out = (float*)d_out;
  float* ws  = (float*)d_ws;

  // output layout: logits[64,256,513] | valid[64,256] | units[256,513] | final[256,1024]
  const size_t OFF_V = (size_t)T_ * B_ * NP_;
  const size_t OFF_U = OFF_V + (size_t)T_ * B_;
  const size_t OFF_F = OFF_U + (size_t)B_ * NP_;

  SkKeys sk = compute_chain();

  pre_kernel<<<dim3(1280), dim3(256), 0, stream>>>(
      ent, key_w, key_b, emb, fc1_w, fc1_b, autm, func_w, func_b,
      fc2_w, fc2_b, ws);

  suh_kernel<<<dim3(B_), dim3(512), LDS_FLOATS * sizeof(float), stream>>>(
      ws, aum, temp, emb, emb_w, emb_b,
      wx, wh, lb, gxg, gxb, ghg, ghb,
      out, out + OFF_V, out + OFF_U, out + OFF_F, sk);
}

// Round 3
// 311.478 us; speedup vs baseline: 1.5922x; 1.3257x over previous
//
#include <hip/hip_runtime.h>
#include <stdint.h>
#include <stddef.h>

// ==== JAX threefry mode: 1 = jax_threefry_partitionable (default in modern JAX)
#define JAX_PARTITIONABLE 1

#define B_   256
#define N_   512
#define NP_  513     // N+1
#define KROW 516     // padded key row stride (floats), 16B-aligned
#define T_   64
#define NEGC 1e9f

// ---------------- threefry2x32 (matches jax/_src/prng.py) ----------------
__host__ __device__ __forceinline__ void tf2x32(uint32_t k0, uint32_t k1,
    uint32_t x0, uint32_t x1, uint32_t& o0, uint32_t& o1) {
  const uint32_t k2 = k0 ^ k1 ^ 0x1BD11BDAu;
#define TFR(r) { x0 += x1; x1 = (x1 << (r)) | (x1 >> (32 - (r))); x1 ^= x0; }
  x0 += k0; x1 += k1;
  TFR(13) TFR(15) TFR(26) TFR(6)
  x0 += k1; x1 += k2 + 1u;
  TFR(17) TFR(29) TFR(16) TFR(24)
  x0 += k2; x1 += k0 + 2u;
  TFR(13) TFR(15) TFR(26) TFR(6)
  x0 += k0; x1 += k1 + 3u;
  TFR(17) TFR(29) TFR(16) TFR(24)
  x0 += k1; x1 += k2 + 4u;
  TFR(13) TFR(15) TFR(26) TFR(6)
  x0 += k2; x1 += k0 + 5u;
#undef TFR
  o0 = x0; o1 = x1;
}

struct SkKeys { uint32_t k[128]; };

static SkKeys compute_chain() {
  SkKeys s;
  uint32_t r0 = 0u, r1 = 42u;   // jax.random.key(42)
  for (int t = 0; t < 64; ++t) {
#if JAX_PARTITIONABLE
    uint32_t a0, a1, b0, b1;
    tf2x32(r0, r1, 0u, 0u, a0, a1);
    tf2x32(r0, r1, 0u, 1u, b0, b1);
    s.k[2*t] = b0; s.k[2*t+1] = b1;
    r0 = a0; r1 = a1;
#else
    uint32_t p0, p1, q0, q1;
    tf2x32(r0, r1, 0u, 2u, p0, p1);
    tf2x32(r0, r1, 1u, 3u, q0, q1);
    s.k[2*t] = p1; s.k[2*t+1] = q1;
    r0 = p0; r1 = q0;
#endif
  }
  return s;
}

__device__ __forceinline__ float gumbel_draw(uint32_t k0, uint32_t k1, int b, int n) {
  uint32_t bits;
#if JAX_PARTITIONABLE
  uint32_t j = (uint32_t)(b * NP_ + n);
  uint32_t o0, o1; tf2x32(k0, k1, 0u, j, o0, o1);
  bits = o0 ^ o1;
#else
  int j = b * NP_ + n;
  uint32_t o0, o1;
  if (j < 65664) { tf2x32(k0, k1, (uint32_t)j, (uint32_t)(j + 65664), o0, o1); bits = o0; }
  else           { tf2x32(k0, k1, (uint32_t)(j - 65664), (uint32_t)j, o0, o1); bits = o1; }
#endif
  float f = __uint_as_float((bits >> 9) | 0x3F800000u) - 1.0f;
  const float TINY = 1.17549435e-38f;
  float u = fmaxf(TINY, f + TINY);
  return -logf(-logf(u));
}

__device__ __forceinline__ float sigm(float x) {
  return 0.5f + 0.5f * tanhf(0.5f * x);   // XLA logistic
}

// barrier with LDS-only drain (no vmcnt: global stores never read back)
__device__ __forceinline__ void bar_lds() {
  asm volatile("s_waitcnt lgkmcnt(0)\n\ts_barrier" ::: "memory");
}

// ---------------- workspace layout (floats) ----------------
#define WS_KEY 0                       // [B][32][KROW] c-major
#define WS_X0  (B_ * 32 * KROW)        // 4,227,072 : [B][32]

// =============== kernel 1: key GEMM (blocks 0..1023) + x0 MLP (1024..1279) ===============
__global__ void __launch_bounds__(256)
pre_kernel(const float* __restrict__ ent, const float* __restrict__ key_w,
           const float* __restrict__ key_b,
           const float* __restrict__ emb, const float* __restrict__ fc1_w,
           const float* __restrict__ fc1_b,
           const float* __restrict__ autm, const float* __restrict__ func_w,
           const float* __restrict__ func_b,
           const float* __restrict__ fc2_w, const float* __restrict__ fc2_b,
           float* __restrict__ ws)
{
  __shared__ __align__(16) float smAll[16384];
  const int tid = threadIdx.x;

  if (blockIdx.x < 1024) {
    float* smA = smAll;            // [64][128] k-major
    float* smW = smAll + 8192;     // [256][32]
    const int blk = blockIdx.x;
    const int R0  = blk * 128;
    const int b   = R0 >> 9;
    const int nb  = R0 & 511;
    const int rg  = tid >> 3;
    const int cg  = tid & 7;

    for (int i = tid; i < 2048; i += 256)
      ((float4*)smW)[i] = ((const float4*)key_w)[i];

    float acc[4][4];
    #pragma unroll
    for (int i = 0; i < 4; ++i)
      #pragma unroll
      for (int j = 0; j < 4; ++j) acc[i][j] = 0.f;

    const int row  = tid >> 1;
    const int half = tid & 1;

    for (int kc = 0; kc < 4; ++kc) {
      const float4* src = (const float4*)(ent + ((size_t)(R0 + row)) * 256 + kc * 64 + half * 32);
      float4 vv[8];
      #pragma unroll
      for (int r = 0; r < 8; ++r) vv[r] = src[r];
      #pragma unroll
      for (int r = 0; r < 8; ++r) {
        const int kl = half * 32 + r * 4;
        smA[(kl + 0) * 128 + row] = vv[r].x;
        smA[(kl + 1) * 128 + row] = vv[r].y;
        smA[(kl + 2) * 128 + row] = vv[r].z;
        smA[(kl + 3) * 128 + row] = vv[r].w;
      }
      __syncthreads();
      #pragma unroll 4
      for (int k = 0; k < 64; ++k) {
        float4 av = *(const float4*)&smA[k * 128 + rg * 4];
        float4 bv = *(const float4*)&smW[(kc * 64 + k) * 32 + cg * 4];
        float ar[4] = {av.x, av.y, av.z, av.w};
        float br[4] = {bv.x, bv.y, bv.z, bv.w};
        #pragma unroll
        for (int i = 0; i < 4; ++i)
          #pragma unroll
          for (int j = 0; j < 4; ++j) acc[i][j] += ar[i] * br[j];
      }
      __syncthreads();
    }
    float4 bb = *(const float4*)&key_b[cg * 4];
    float bbr[4] = {bb.x, bb.y, bb.z, bb.w};
    #pragma unroll
    for (int j = 0; j < 4; ++j) {
      const int c = cg * 4 + j;
      float* dst = ws + WS_KEY + ((size_t)(b * 32 + c)) * KROW + nb + rg * 4;
      #pragma unroll
      for (int i = 0; i < 4; ++i) dst[i] = acc[i][j] + bbr[j];
    }
  } else {
    float* smX = smAll;
    const int b = blockIdx.x - 1024;
    const int j = tid;
    {
      float a = 0.f;
      const float* e = emb + (size_t)b * 1024;
      #pragma unroll 8
      for (int k = 0; k < 1024; ++k) a += e[k] * fc1_w[k * 256 + j];
      a = fmaxf(a + fc1_b[j], 0.f);
      float f = 0.f;
      const float* m = autm + (size_t)b * 259;
      for (int k = 0; k < 259; ++k) f += m[k] * func_w[k * 256 + j];
      f = fmaxf(f + func_b[j], 0.f);
      smX[j] = a + f;
    }
    __syncthreads();
    if (j < 32) {
      float s = 0.f;
      #pragma unroll 8
      for (int m = 0; m < 256; ++m) s += smX[m] * fc2_w[m * 32 + j];
      ws[WS_X0 + b * 32 + j] = fmaxf(s + fc2_b[j], 0.f);
    }
  }
}

// =============== kernel 2: scan ===============
// LDS layout (floats)
#define OFF_KEY   0        // 32*516 = 16512, c-major [32][516]
#define OFF_WB    16512    // 8192: wx[32][128] | wh[32][128]
#define OFF_MASK  24704    // 513 (pad to 25220)
#define OFF_UNITS 25220    // 513 (pad to 25736)
#define OFF_GUM   25736    // 513 (pad to 26252)
#define OFF_LNH   26252    // 128
#define OFF_XS    26380    // 32
#define OFF_HS    26412    // 32
#define OFF_RV    26444    // 2
#define OFF_RI    26446    // 2 (ints aliased)
#define OFF_ES    26452    // 32
#define OFF_PART  26484    // 512
#define LDS_FLOATS 26996

__global__ void __launch_bounds__(512)
suh_kernel(const float* __restrict__ ws_key_x0,
           const float* __restrict__ aum, const float* __restrict__ temp_p,
           const float* __restrict__ emb,
           const float* __restrict__ emb_w, const float* __restrict__ emb_b,
           const float* __restrict__ wx, const float* __restrict__ wh,
           const float* __restrict__ lstm_bb,
           const float* __restrict__ ln_gx, const float* __restrict__ ln_bx,
           const float* __restrict__ ln_gh, const float* __restrict__ ln_bh,
           float* __restrict__ out_logits, float* __restrict__ out_valid,
           float* __restrict__ out_units, float* __restrict__ out_final,
           SkKeys sk)
{
  extern __shared__ __align__(16) float sm[];
  int* smi = (int*)sm;
  const int b   = blockIdx.x;
  const int tid = threadIdx.x;

  // ---------- prologue ----------
  {
    const float4* kv = (const float4*)(ws_key_x0 + WS_KEY + (size_t)b * (32 * KROW));
    for (int i = tid; i < (32 * KROW) / 4; i += 512) ((float4*)sm)[i] = kv[i];
  }
  for (int i = tid; i < 1024; i += 512) ((float4*)(sm + OFF_WB))[i]        = ((const float4*)wx)[i];
  for (int i = tid; i < 1024; i += 512) ((float4*)(sm + OFF_WB + 4096))[i] = ((const float4*)wh)[i];
  {
    const float* am = aum + (size_t)b * N_;
    for (int n = tid; n < NP_; n += 512) {
      sm[OFF_MASK + n]  = (n < N_) ? am[n] : 1.0f;
      sm[OFF_UNITS + n] = 0.f;
    }
  }
  if (tid < 32) {
    sm[OFF_XS + tid] = ws_key_x0[WS_X0 + b * 32 + tid];
    sm[OFF_HS + tid] = 0.f;
  }
  __syncthreads();
  if (tid < 32) sm[OFF_KEY + tid * KROW + N_] = 0.f;   // appended zero key row
  __syncthreads();

  const float temp = temp_p[0];

  // hoisted per-lane LN params (wave0: gx side + lstm bias; wave1: gh side)
  float gxg0=0.f, gxg1=0.f, gxb0=0.f, gxb1=0.f, lb0=0.f, lb1=0.f;
  float ghg0=0.f, ghg1=0.f, ghb0=0.f, ghb1=0.f;
  if (tid < 64) {
    gxg0 = ln_gx[tid]; gxg1 = ln_gx[tid + 64];
    gxb0 = ln_bx[tid]; gxb1 = ln_bx[tid + 64];
    lb0  = lstm_bb[tid]; lb1 = lstm_bb[tid + 64];
  } else if (tid < 128) {
    const int l = tid - 64;
    ghg0 = ln_gh[l]; ghg1 = ln_gh[l + 64];
    ghb0 = ln_bh[l]; ghb1 = ln_bh[l + 64];
  }

  float creg = 0.f;       // cell state, lanes 0..31 of wave0
  int done_reg = 0;       // tid==128 only

  // ---------- 64-step scan (3 barriers/step) ----------
  for (int t = 0; t < T_; ++t) {
    const uint32_t kk0 = sk.k[2 * t], kk1 = sk.k[2 * t + 1];
    float lnx0 = 0.f, lnx1 = 0.f;

    // ---- Phase A ----
    if (tid < 64) {
      // wave0: gx + LN(x) in-register
      float xr[32];
      #pragma unroll
      for (int r = 0; r < 8; ++r) {
        float4 v = *(const float4*)&sm[OFF_XS + r * 4];
        xr[r*4] = v.x; xr[r*4+1] = v.y; xr[r*4+2] = v.z; xr[r*4+3] = v.w;
      }
      float a0 = 0.f, a1 = 0.f;
      #pragma unroll
      for (int k = 0; k < 32; ++k) {
        a0 += xr[k] * sm[OFF_WB + k * 128 + tid];
        a1 += xr[k] * sm[OFF_WB + k * 128 + tid + 64];
      }
      float s = a0 + a1;
      for (int off = 32; off; off >>= 1) s += __shfl_down(s, off);
      float m = __shfl(s, 0) * (1.0f / 128.0f);
      float d0 = a0 - m, d1 = a1 - m;
      float ss = d0 * d0 + d1 * d1;
      for (int off = 32; off; off >>= 1) ss += __shfl_down(ss, off);
      float var = __shfl(ss, 0) * (1.0f / 128.0f);
      float rstd = 1.0f / sqrtf(var + 1e-5f);
      lnx0 = d0 * rstd * gxg0 + gxb0;
      lnx1 = d1 * rstd * gxg1 + gxb1;
    } else if (tid < 128) {
      // wave1: gh + LN(h) -> LDS
      const int l = tid - 64;
      float hr2[32];
      #pragma unroll
      for (int r = 0; r < 8; ++r) {
        float4 v = *(const float4*)&sm[OFF_HS + r * 4];
        hr2[r*4] = v.x; hr2[r*4+1] = v.y; hr2[r*4+2] = v.z; hr2[r*4+3] = v.w;
      }
      float a0 = 0.f, a1 = 0.f;
      #pragma unroll
      for (int k = 0; k < 32; ++k) {
        a0 += hr2[k] * sm[OFF_WB + 4096 + k * 128 + l];
        a1 += hr2[k] * sm[OFF_WB + 4096 + k * 128 + l + 64];
      }
      float s = a0 + a1;
      for (int off = 32; off; off >>= 1) s += __shfl_down(s, off);
      float m = __shfl(s, 0) * (1.0f / 128.0f);
      float d0 = a0 - m, d1 = a1 - m;
      float ss = d0 * d0 + d1 * d1;
      for (int off = 32; off; off >>= 1) ss += __shfl_down(ss, off);
      float var = __shfl(ss, 0) * (1.0f / 128.0f);
      float rstd = 1.0f / sqrtf(var + 1e-5f);
      sm[OFF_LNH + l]      = d0 * rstd * ghg0 + ghb0;
      sm[OFF_LNH + 64 + l] = d1 * rstd * ghg1 + ghb1;
    } else if (tid == 128) {
      // apply previous step's selection (hidden under gate GEMMs)
      if (t > 0) {
        float r0v = sm[OFF_RV], r1v = sm[OFF_RV + 1];
        int   r0i = smi[OFF_RI], r1i = smi[OFF_RI + 1];
        float bvv; int bii;
        if (r1v > r0v || (r1v == r0v && r1i < r0i)) { bvv = r1v; bii = r1i; }
        else                                        { bvv = r0v; bii = r0i; }
        const int active = !done_reg;
        const int is_end = (bii == N_);
        out_valid[(size_t)(t - 1) * B_ + b] = active ? 1.0f : 0.0f;
        if (active && !is_end) { sm[OFF_UNITS + bii] = 1.0f; sm[OFF_MASK + bii] = 0.0f; }
        if (active && is_end) done_reg = 1;
      }
    } else if (tid >= 192) {
      // waves 3-7: gumbels for THIS step
      const int n = tid - 192;                    // 0..319
      sm[OFF_GUM + n] = gumbel_draw(kk0, kk1, b, n);
      if (n < 192) sm[OFF_GUM + 320 + n] = gumbel_draw(kk0, kk1, b, 320 + n);
      if (n == 192) sm[OFF_GUM + 512]    = gumbel_draw(kk0, kk1, b, 512);
    }
    bar_lds();                                    // bar1

    // ---- Phase B: gates + cell (wave0) ----
    if (tid < 64) {
      float lh0 = sm[OFF_LNH + tid], lh1 = sm[OFF_LNH + 64 + tid];
      float g0 = lnx0 + lh0 + lb0;     // gate[tid]      (i|f half)
      float g1 = lnx1 + lh1 + lb1;     // gate[tid+64]   (o|u half)
      float fq = __shfl(g0, tid + 32); // gate[tid+32] for tid<32
      float uq = __shfl(g1, tid + 32); // gate[tid+96] for tid<32
      if (tid < 32) {
        float cN = sigm(fq) * creg + sigm(g0) * tanhf(uq);
        float hN = sigm(g1) * tanhf(cN);
        creg = cN;
        sm[OFF_HS + tid] = hN;
        sm[OFF_XS + tid] = hN;
      }
    }
    bar_lds();                                    // bar2

    // ---- Phase C: pointer scores + argmax partials (waves 0-1) ----
    if (tid < 128) {
      const int g = tid;
      float4 h4[8];
      #pragma unroll
      for (int r = 0; r < 8; ++r) h4[r] = *(const float4*)&sm[OFF_HS + r * 4];
      float hr[32] = {h4[0].x,h4[0].y,h4[0].z,h4[0].w, h4[1].x,h4[1].y,h4[1].z,h4[1].w,
                      h4[2].x,h4[2].y,h4[2].z,h4[2].w, h4[3].x,h4[3].y,h4[3].z,h4[3].w,
                      h4[4].x,h4[4].y,h4[4].z,h4[4].w, h4[5].x,h4[5].y,h4[5].z,h4[5].w,
                      h4[6].x,h4[6].y,h4[6].z,h4[6].w, h4[7].x,h4[7].y,h4[7].z,h4[7].w};
      float ac0 = 0.f, ac1 = 0.f, ac2 = 0.f, ac3 = 0.f;
      #pragma unroll
      for (int k = 0; k < 32; ++k) {
        float4 kv = *(const float4*)&sm[OFF_KEY + k * KROW + g * 4];
        float hk = hr[k];
        ac0 += hk * kv.x; ac1 += hk * kv.y; ac2 += hk * kv.z; ac3 += hk * kv.w;
      }
      float4 mv = *(const float4*)&sm[OFF_MASK + g * 4];
      float4 gv = *(const float4*)&sm[OFF_GUM + g * 4];
      float q0 = ac0 * (1.0f/32.0f) - (1.0f - mv.x) * NEGC;
      float q1 = ac1 * (1.0f/32.0f) - (1.0f - mv.y) * NEGC;
      float q2 = ac2 * (1.0f/32.0f) - (1.0f - mv.z) * NEGC;
      float q3 = ac3 * (1.0f/32.0f) - (1.0f - mv.w) * NEGC;
      float* lrow = out_logits + ((size_t)t * B_ + b) * NP_;
      lrow[g*4    ] = q0; lrow[g*4 + 1] = q1;
      lrow[g*4 + 2] = q2; lrow[g*4 + 3] = q3;
      float v0 = q0 / temp + gv.x;
      float v1 = q1 / temp + gv.y;
      float v2 = q2 / temp + gv.z;
      float v3 = q3 / temp + gv.w;
      float bv = v0; int bi = g*4;
      if (v1 > bv) { bv = v1; bi = g*4 + 1; }
      if (v2 > bv) { bv = v2; bi = g*4 + 2; }
      if (v3 > bv) { bv = v3; bi = g*4 + 3; }
      if (g == 0) {
        float q = -(1.0f - sm[OFF_MASK + N_]) * NEGC;   // zero key row: dot == 0
        lrow[N_] = q;
        float v = q / temp + sm[OFF_GUM + N_];
        if (v > bv) { bv = v; bi = N_; }
      }
      for (int off = 32; off; off >>= 1) {
        float ov = __shfl_down(bv, off);
        int   oi = __shfl_down(bi, off);
        if (ov > bv || (ov == bv && oi < bi)) { bv = ov; bi = oi; }
      }
      if ((tid & 63) == 0) { sm[OFF_RV + (tid >> 6)] = bv; smi[OFF_RI + (tid >> 6)] = bi; }
    }
    bar_lds();                                    // bar3
  }

  // final selection (t = 63)
  if (tid == 128) {
    float r0v = sm[OFF_RV], r1v = sm[OFF_RV + 1];
    int   r0i = smi[OFF_RI], r1i = smi[OFF_RI + 1];
    float bvv; int bii;
    if (r1v > r0v || (r1v == r0v && r1i < r0i)) { bvv = r1v; bii = r1i; }
    else                                        { bvv = r0v; bii = r0i; }
    (void)bvv;
    const int active = !done_reg;
    const int is_end = (bii == N_);
    out_valid[(size_t)(T_ - 1) * B_ + b] = active ? 1.0f : 0.0f;
    if (active && !is_end) { sm[OFF_UNITS + bii] = 1.0f; sm[OFF_MASK + bii] = 0.0f; }
  }
  __syncthreads();

  // ---------- epilogue: emb_sel & final ----------
  {
    const int g = tid >> 5, cc = tid & 31;
    float p = 0.f;
    const int n0 = g * 32;
    for (int nn = 0; nn < 32; ++nn) {
      const int n = n0 + nn;
      p += sm[OFF_UNITS + n] * sm[OFF_KEY + cc * KROW + n];
    }
    if (g == 15) p += sm[OFF_UNITS + N_] * sm[OFF_KEY + cc * KROW + N_];
    sm[OFF_PART + g * 32 + cc] = p;
  }
  for (int n = tid; n < NP_; n += 512) out_units[(size_t)b * NP_ + n] = sm[OFF_UNITS + n];
  __syncthreads();
  if (tid < 32) {
    float s = 0.f;
    #pragma unroll
    for (int g = 0; g < 16; ++g) s += sm[OFF_PART + g * 32 + tid];
    sm[OFF_ES + tid] = s / 513.0f;
  }
  __syncthreads();
  {
    const float* e = emb + (size_t)b * 1024;
    for (int d = tid; d < 1024; d += 512) {
      float a = 0.f;
      #pragma unroll
      for (int k = 0; k < 32; ++k) a += sm[OFF_ES + k] * emb_w[k * 1024 + d];
      out_final[(size_t)b * 1024 + d] = e[d] + a + emb_b[d];
    }
  }
}

extern "C" void kernel_launch(void* const* d_in, const int* in_sizes, int n_in,
                              void* d_out, int out_size, void* d_ws, size_t ws_size,
                              hipStream_t stream) {
  (void)in_sizes; (void)n_in; (void)ws_size; (void)out_size;
  const float* emb    = (const float*)d_in[0];
  const float* autm   = (const float*)d_in[1];
  const float* aum    = (const float*)d_in[2];
  const float* ent    = (const float*)d_in[3];
  const float* temp   = (const float*)d_in[4];
  const float* key_w  = (const float*)d_in[5];
  const float* key_b  = (const float*)d_in[6];
  const float* func_w = (const float*)d_in[7];
  const float* func_b = (const float*)d_in[8];
  const float* fc1_w  = (const float*)d_in[9];
  const float* fc1_b  = (const float*)d_in[10];
  const float* fc2_w  = (const float*)d_in[11];
  const float* fc2_b  = (const float*)d_in[12];
  const float* emb_w  = (const float*)d_in[13];
  const float* emb_b  = (const float*)d_in[14];
  const float* wx     = (const float*)d_in[15];
  const float* wh     = (const float*)d_in[16];
  const float* lb     = (const float*)d_in[17];
  const float* gxg    = (const float*)d_in[18];
  const float* gxb    = (const float*)d_in[19];
  const float* ghg    = (const float*)d_in[20];
  const float* ghb    = (const float*)d_in[21];
  float* out = (float*)d_out;
  float* ws  = (float*)d_ws;

  // output layout: logits[64,256,513] | valid[64,256] | units[256,513] | final[256,1024]
  const size_t OFF_V = (size_t)T_ * B_ * NP_;
  const size_t OFF_U = OFF_V + (size_t)T_ * B_;
  const size_t OFF_F = OFF_U + (size_t)B_ * NP_;

  SkKeys sk = compute_chain();

  pre_kernel<<<dim3(1280), dim3(256), 0, stream>>>(
      ent, key_w, key_b, emb, fc1_w, fc1_b, autm, func_w, func_b,
      fc2_w, fc2_b, ws);

  suh_kernel<<<dim3(B_), dim3(512), LDS_FLOATS * sizeof(float), stream>>>(
      ws, aum, temp, emb, emb_w, emb_b,
      wx, wh, lb, gxg, gxb, ghg, ghb,
      out, out + OFF_V, out + OFF_U, out + OFF_F, sk);
}

// Round 4
// 300.790 us; speedup vs baseline: 1.6487x; 1.0355x over previous
//
#include <hip/hip_runtime.h>
#include <stdint.h>
#include <stddef.h>

// ==== JAX threefry mode: 1 = jax_threefry_partitionable (default in modern JAX)
#define JAX_PARTITIONABLE 1

#define B_   256
#define N_   512
#define NP_  513     // N+1
#define KROW 516     // padded key row stride (floats), 16B-aligned
#define T_   64
#define NEGC 1e9f

// ---------------- threefry2x32 (matches jax/_src/prng.py) ----------------
__host__ __device__ __forceinline__ void tf2x32(uint32_t k0, uint32_t k1,
    uint32_t x0, uint32_t x1, uint32_t& o0, uint32_t& o1) {
  const uint32_t k2 = k0 ^ k1 ^ 0x1BD11BDAu;
#define TFR(r) { x0 += x1; x1 = (x1 << (r)) | (x1 >> (32 - (r))); x1 ^= x0; }
  x0 += k0; x1 += k1;
  TFR(13) TFR(15) TFR(26) TFR(6)
  x0 += k1; x1 += k2 + 1u;
  TFR(17) TFR(29) TFR(16) TFR(24)
  x0 += k2; x1 += k0 + 2u;
  TFR(13) TFR(15) TFR(26) TFR(6)
  x0 += k0; x1 += k1 + 3u;
  TFR(17) TFR(29) TFR(16) TFR(24)
  x0 += k1; x1 += k2 + 4u;
  TFR(13) TFR(15) TFR(26) TFR(6)
  x0 += k2; x1 += k0 + 5u;
#undef TFR
  o0 = x0; o1 = x1;
}

struct SkKeys { uint32_t k[128]; };

static SkKeys compute_chain() {
  SkKeys s;
  uint32_t r0 = 0u, r1 = 42u;   // jax.random.key(42)
  for (int t = 0; t < 64; ++t) {
#if JAX_PARTITIONABLE
    uint32_t a0, a1, b0, b1;
    tf2x32(r0, r1, 0u, 0u, a0, a1);
    tf2x32(r0, r1, 0u, 1u, b0, b1);
    s.k[2*t] = b0; s.k[2*t+1] = b1;
    r0 = a0; r1 = a1;
#else
    uint32_t p0, p1, q0, q1;
    tf2x32(r0, r1, 0u, 2u, p0, p1);
    tf2x32(r0, r1, 1u, 3u, q0, q1);
    s.k[2*t] = p1; s.k[2*t+1] = q1;
    r0 = p0; r1 = q0;
#endif
  }
  return s;
}

__device__ __forceinline__ float gumbel_draw(uint32_t k0, uint32_t k1, int b, int n) {
  uint32_t bits;
#if JAX_PARTITIONABLE
  uint32_t j = (uint32_t)(b * NP_ + n);
  uint32_t o0, o1; tf2x32(k0, k1, 0u, j, o0, o1);
  bits = o0 ^ o1;
#else
  int j = b * NP_ + n;
  uint32_t o0, o1;
  if (j < 65664) { tf2x32(k0, k1, (uint32_t)j, (uint32_t)(j + 65664), o0, o1); bits = o0; }
  else           { tf2x32(k0, k1, (uint32_t)(j - 65664), (uint32_t)j, o0, o1); bits = o1; }
#endif
  float f = __uint_as_float((bits >> 9) | 0x3F800000u) - 1.0f;
  const float TINY = 1.17549435e-38f;
  float u = fmaxf(TINY, f + TINY);
  return -logf(-logf(u));
}

__device__ __forceinline__ float sigm(float x) {
  return 0.5f + 0.5f * tanhf(0.5f * x);   // XLA logistic
}

// barrier with LDS-only drain (no vmcnt: global stores never read back)
__device__ __forceinline__ void bar_lds() {
  asm volatile("s_waitcnt lgkmcnt(0)\n\ts_barrier" ::: "memory");
}

// ---------------- workspace layout (floats) ----------------
#define WS_KEY 0                       // [B][32][KROW] c-major
#define WS_X0  (B_ * 32 * KROW)        // [B][32]

// =============== kernel 1: key GEMM (blocks 0..1023) + x0 MLP (1024..1279) ===============
__global__ void __launch_bounds__(256)
pre_kernel(const float* __restrict__ ent, const float* __restrict__ key_w,
           const float* __restrict__ key_b,
           const float* __restrict__ emb, const float* __restrict__ fc1_w,
           const float* __restrict__ fc1_b,
           const float* __restrict__ autm, const float* __restrict__ func_w,
           const float* __restrict__ func_b,
           const float* __restrict__ fc2_w, const float* __restrict__ fc2_b,
           float* __restrict__ ws)
{
  __shared__ __align__(16) float smAll[16384];
  const int tid = threadIdx.x;

  if (blockIdx.x < 1024) {
    float* smA = smAll;            // [64][128] k-major
    float* smW = smAll + 8192;     // [256][32]
    const int blk = blockIdx.x;
    const int R0  = blk * 128;
    const int b   = R0 >> 9;
    const int nb  = R0 & 511;
    const int rg  = tid >> 3;
    const int cg  = tid & 7;

    for (int i = tid; i < 2048; i += 256)
      ((float4*)smW)[i] = ((const float4*)key_w)[i];

    float acc[4][4];
    #pragma unroll
    for (int i = 0; i < 4; ++i)
      #pragma unroll
      for (int j = 0; j < 4; ++j) acc[i][j] = 0.f;

    const int row  = tid >> 1;
    const int half = tid & 1;

    for (int kc = 0; kc < 4; ++kc) {
      const float4* src = (const float4*)(ent + ((size_t)(R0 + row)) * 256 + kc * 64 + half * 32);
      float4 vv[8];
      #pragma unroll
      for (int r = 0; r < 8; ++r) vv[r] = src[r];
      #pragma unroll
      for (int r = 0; r < 8; ++r) {
        const int kl = half * 32 + r * 4;
        smA[(kl + 0) * 128 + row] = vv[r].x;
        smA[(kl + 1) * 128 + row] = vv[r].y;
        smA[(kl + 2) * 128 + row] = vv[r].z;
        smA[(kl + 3) * 128 + row] = vv[r].w;
      }
      __syncthreads();
      #pragma unroll 4
      for (int k = 0; k < 64; ++k) {
        float4 av = *(const float4*)&smA[k * 128 + rg * 4];
        float4 bv = *(const float4*)&smW[(kc * 64 + k) * 32 + cg * 4];
        float ar[4] = {av.x, av.y, av.z, av.w};
        float br[4] = {bv.x, bv.y, bv.z, bv.w};
        #pragma unroll
        for (int i = 0; i < 4; ++i)
          #pragma unroll
          for (int j = 0; j < 4; ++j) acc[i][j] += ar[i] * br[j];
      }
      __syncthreads();
    }
    float4 bb = *(const float4*)&key_b[cg * 4];
    float bbr[4] = {bb.x, bb.y, bb.z, bb.w};
    #pragma unroll
    for (int j = 0; j < 4; ++j) {
      const int c = cg * 4 + j;
      float* dst = ws + WS_KEY + ((size_t)(b * 32 + c)) * KROW + nb + rg * 4;
      #pragma unroll
      for (int i = 0; i < 4; ++i) dst[i] = acc[i][j] + bbr[j];
    }
  } else {
    float* smX = smAll;
    const int b = blockIdx.x - 1024;
    const int j = tid;
    {
      float a = 0.f;
      const float* e = emb + (size_t)b * 1024;
      #pragma unroll 8
      for (int k = 0; k < 1024; ++k) a += e[k] * fc1_w[k * 256 + j];
      a = fmaxf(a + fc1_b[j], 0.f);
      float f = 0.f;
      const float* m = autm + (size_t)b * 259;
      for (int k = 0; k < 259; ++k) f += m[k] * func_w[k * 256 + j];
      f = fmaxf(f + func_b[j], 0.f);
      smX[j] = a + f;
    }
    __syncthreads();
    if (j < 32) {
      float s = 0.f;
      #pragma unroll 8
      for (int m = 0; m < 256; ++m) s += smX[m] * fc2_w[m * 32 + j];
      ws[WS_X0 + b * 32 + j] = fmaxf(s + fc2_b[j], 0.f);
    }
  }
}

// =============== kernel 2: scan ===============
// LDS layout (floats)
#define OFF_KEY   0        // 32*516 = 16512, c-major [32][516]
#define OFF_MASK  16512    // 513 (pad to 516)
#define OFF_UNITS 17028    // 513 (pad to 516)
#define OFF_GUM   17544    // 513 (pad to 516)
#define OFF_HS    18060    // 32
#define OFF_RV    18092    // 2
#define OFF_RI    18094    // 2 (ints aliased)
#define OFF_ES    18096    // 32
#define OFF_PART  18128    // 512
#define LDS_FLOATS 18640

__global__ void __launch_bounds__(512)
suh_kernel(const float* __restrict__ ws_key_x0,
           const float* __restrict__ aum, const float* __restrict__ temp_p,
           const float* __restrict__ emb,
           const float* __restrict__ emb_w, const float* __restrict__ emb_b,
           const float* __restrict__ wx, const float* __restrict__ wh,
           const float* __restrict__ lstm_bb,
           const float* __restrict__ ln_gx, const float* __restrict__ ln_bx,
           const float* __restrict__ ln_gh, const float* __restrict__ ln_bh,
           float* __restrict__ out_logits, float* __restrict__ out_valid,
           float* __restrict__ out_units, float* __restrict__ out_final,
           SkKeys sk)
{
  extern __shared__ __align__(16) float sm[];
  int* smi = (int*)sm;
  const int b   = blockIdx.x;
  const int tid = threadIdx.x;
  const int l6  = tid & 63;

  // ---------- prologue ----------
  {
    const float4* kv = (const float4*)(ws_key_x0 + WS_KEY + (size_t)b * (32 * KROW));
    for (int i = tid; i < (32 * KROW) / 4; i += 512) ((float4*)sm)[i] = kv[i];
  }
  {
    const float* am = aum + (size_t)b * N_;
    for (int n = tid; n < NP_; n += 512) {
      sm[OFF_MASK + n]  = (n < N_) ? am[n] : 1.0f;
      sm[OFF_UNITS + n] = 0.f;
    }
  }
  __syncthreads();
  if (tid < 32) sm[OFF_KEY + tid * KROW + N_] = 0.f;   // appended zero key row
  __syncthreads();

  const float temp = temp_p[0];

  // persistent per-lane LSTM weights (wave0 uses them; loads uniform across waves, in-bounds)
  float wxr0[32], wxr1[32], whr0[32], whr1[32];
  #pragma unroll
  for (int k = 0; k < 32; ++k) {
    wxr0[k] = wx[k * 128 + l6];
    wxr1[k] = wx[k * 128 + 64 + l6];
    whr0[k] = wh[k * 128 + l6];
    whr1[k] = wh[k * 128 + 64 + l6];
  }
  // LN params (lane l owns gate cols l and l+64)
  float gxg0=0.f, gxg1=0.f, gxb0=0.f, gxb1=0.f, lb0=0.f, lb1=0.f;
  float ghg0=0.f, ghg1=0.f, ghb0=0.f, ghb1=0.f;
  if (tid < 64) {
    gxg0 = ln_gx[tid]; gxg1 = ln_gx[tid + 64];
    gxb0 = ln_bx[tid]; gxb1 = ln_bx[tid + 64];
    ghg0 = ln_gh[tid]; ghg1 = ln_gh[tid + 64];
    ghb0 = ln_bh[tid]; ghb1 = ln_bh[tid + 64];
    lb0  = lstm_bb[tid]; lb1 = lstm_bb[tid + 64];
  }

  float creg = 0.f;       // cell state, lanes 0..31 of wave0
  int done_reg = 0;       // tid==511 only

  // ---------- 64-step scan (2 barriers/step) ----------
  for (int t = 0; t < T_; ++t) {
    const uint32_t kk0 = sk.k[2 * t], kk1 = sk.k[2 * t + 1];

    // ---- Phase 1 ----
    if (tid < 64) {
      // wave0: full LN-LSTM step in-register
      float xfrag[32];
      if (t == 0) {
        const float* x0g = ws_key_x0 + WS_X0 + b * 32;
        #pragma unroll
        for (int r = 0; r < 8; ++r) {
          float4 v = *(const float4*)(x0g + r * 4);
          xfrag[r*4] = v.x; xfrag[r*4+1] = v.y; xfrag[r*4+2] = v.z; xfrag[r*4+3] = v.w;
        }
      } else {
        #pragma unroll
        for (int r = 0; r < 8; ++r) {
          float4 v = *(const float4*)&sm[OFF_HS + r * 4];
          xfrag[r*4] = v.x; xfrag[r*4+1] = v.y; xfrag[r*4+2] = v.z; xfrag[r*4+3] = v.w;
        }
      }
      float a0 = 0.f, a1 = 0.f, b0 = 0.f, b1 = 0.f;
      #pragma unroll
      for (int k = 0; k < 32; ++k) {
        a0 += xfrag[k] * wxr0[k];
        a1 += xfrag[k] * wxr1[k];
      }
      if (t > 0) {                       // at t==0, h==0 -> gh exactly 0
        #pragma unroll
        for (int k = 0; k < 32; ++k) {
          b0 += xfrag[k] * whr0[k];
          b1 += xfrag[k] * whr1[k];
        }
      }
      // interleaved LN butterflies (same pairing order as the passing kernel)
      float sx = a0 + a1, sh = b0 + b1;
      for (int off = 32; off; off >>= 1) {
        sx += __shfl_down(sx, off);
        sh += __shfl_down(sh, off);
      }
      float mx  = __shfl(sx, 0) * (1.0f / 128.0f);
      float mhh = __shfl(sh, 0) * (1.0f / 128.0f);
      float dx0 = a0 - mx, dx1 = a1 - mx;
      float dh0 = b0 - mhh, dh1 = b1 - mhh;
      float ssx = dx0 * dx0 + dx1 * dx1;
      float ssh = dh0 * dh0 + dh1 * dh1;
      for (int off = 32; off; off >>= 1) {
        ssx += __shfl_down(ssx, off);
        ssh += __shfl_down(ssh, off);
      }
      float vx = __shfl(ssx, 0) * (1.0f / 128.0f);
      float vh = __shfl(ssh, 0) * (1.0f / 128.0f);
      float rx = 1.0f / sqrtf(vx + 1e-5f);
      float rh = 1.0f / sqrtf(vh + 1e-5f);
      float lnx0 = dx0 * rx * gxg0 + gxb0;
      float lnx1 = dx1 * rx * gxg1 + gxb1;
      float lnh0 = dh0 * rh * ghg0 + ghb0;
      float lnh1 = dh1 * rh * ghg1 + ghb1;
      float g0 = lnx0 + lnh0 + lb0;      // gate[tid]     (i|f half)
      float g1 = lnx1 + lnh1 + lb1;      // gate[tid+64]  (o|u half)
      float fq = __shfl(g0, tid + 32);
      float uq = __shfl(g1, tid + 32);
      if (tid < 32) {
        float cN = sigm(fq) * creg + sigm(g0) * tanhf(uq);
        float hN = sigm(g1) * tanhf(cN);
        creg = cN;
        sm[OFF_HS + tid] = hN;
      }
    } else {
      // waves 1-7: gumbels for THIS step
      const int n = tid - 64;                    // 0..447
      sm[OFF_GUM + n] = gumbel_draw(kk0, kk1, b, n);
      if (tid < 129) sm[OFF_GUM + 448 + n] = gumbel_draw(kk0, kk1, b, 448 + n);
      if (tid == 511 && t > 0) {
        // apply previous step's selection (hidden under LSTM work)
        float r0v = sm[OFF_RV], r1v = sm[OFF_RV + 1];
        int   r0i = smi[OFF_RI], r1i = smi[OFF_RI + 1];
        float bvv; int bii;
        if (r1v > r0v || (r1v == r0v && r1i < r0i)) { bvv = r1v; bii = r1i; }
        else                                        { bvv = r0v; bii = r0i; }
        (void)bvv;
        const int active = !done_reg;
        const int is_end = (bii == N_);
        out_valid[(size_t)(t - 1) * B_ + b] = active ? 1.0f : 0.0f;
        if (active && !is_end) { sm[OFF_UNITS + bii] = 1.0f; sm[OFF_MASK + bii] = 0.0f; }
        if (active && is_end) done_reg = 1;
      }
    }
    bar_lds();                                    // bar1

    // ---- Phase 2: pointer scores + argmax partials (waves 0-1) ----
    if (tid < 128) {
      const int g = tid;
      float4 h4[8];
      #pragma unroll
      for (int r = 0; r < 8; ++r) h4[r] = *(const float4*)&sm[OFF_HS + r * 4];
      float hr[32] = {h4[0].x,h4[0].y,h4[0].z,h4[0].w, h4[1].x,h4[1].y,h4[1].z,h4[1].w,
                      h4[2].x,h4[2].y,h4[2].z,h4[2].w, h4[3].x,h4[3].y,h4[3].z,h4[3].w,
                      h4[4].x,h4[4].y,h4[4].z,h4[4].w, h4[5].x,h4[5].y,h4[5].z,h4[5].w,
                      h4[6].x,h4[6].y,h4[6].z,h4[6].w, h4[7].x,h4[7].y,h4[7].z,h4[7].w};
      float ac0 = 0.f, ac1 = 0.f, ac2 = 0.f, ac3 = 0.f;
      #pragma unroll
      for (int k = 0; k < 32; ++k) {
        float4 kv = *(const float4*)&sm[OFF_KEY + k * KROW + g * 4];
        float hk = hr[k];
        ac0 += hk * kv.x; ac1 += hk * kv.y; ac2 += hk * kv.z; ac3 += hk * kv.w;
      }
      float4 mv = *(const float4*)&sm[OFF_MASK + g * 4];
      float4 gv = *(const float4*)&sm[OFF_GUM + g * 4];
      float q0 = ac0 * (1.0f/32.0f) - (1.0f - mv.x) * NEGC;
      float q1 = ac1 * (1.0f/32.0f) - (1.0f - mv.y) * NEGC;
      float q2 = ac2 * (1.0f/32.0f) - (1.0f - mv.z) * NEGC;
      float q3 = ac3 * (1.0f/32.0f) - (1.0f - mv.w) * NEGC;
      float* lrow = out_logits + ((size_t)t * B_ + b) * NP_;
      lrow[g*4    ] = q0; lrow[g*4 + 1] = q1;
      lrow[g*4 + 2] = q2; lrow[g*4 + 3] = q3;
      float v0 = q0 / temp + gv.x;
      float v1 = q1 / temp + gv.y;
      float v2 = q2 / temp + gv.z;
      float v3 = q3 / temp + gv.w;
      float bv = v0; int bi = g*4;
      if (v1 > bv) { bv = v1; bi = g*4 + 1; }
      if (v2 > bv) { bv = v2; bi = g*4 + 2; }
      if (v3 > bv) { bv = v3; bi = g*4 + 3; }
      if (g == 0) {
        float q = -(1.0f - sm[OFF_MASK + N_]) * NEGC;   // zero key row: dot == 0
        lrow[N_] = q;
        float v = q / temp + sm[OFF_GUM + N_];
        if (v > bv) { bv = v; bi = N_; }
      }
      for (int off = 32; off; off >>= 1) {
        float ov = __shfl_down(bv, off);
        int   oi = __shfl_down(bi, off);
        if (ov > bv || (ov == bv && oi < bi)) { bv = ov; bi = oi; }
      }
      if ((tid & 63) == 0) { sm[OFF_RV + (tid >> 6)] = bv; smi[OFF_RI + (tid >> 6)] = bi; }
    }
    bar_lds();                                    // bar2
  }

  // final selection (t = 63)
  if (tid == 511) {
    float r0v = sm[OFF_RV], r1v = sm[OFF_RV + 1];
    int   r0i = smi[OFF_RI], r1i = smi[OFF_RI + 1];
    float bvv; int bii;
    if (r1v > r0v || (r1v == r0v && r1i < r0i)) { bvv = r1v; bii = r1i; }
    else                                        { bvv = r0v; bii = r0i; }
    (void)bvv;
    const int active = !done_reg;
    const int is_end = (bii == N_);
    out_valid[(size_t)(T_ - 1) * B_ + b] = active ? 1.0f : 0.0f;
    if (active && !is_end) { sm[OFF_UNITS + bii] = 1.0f; sm[OFF_MASK + bii] = 0.0f; }
  }
  __syncthreads();

  // ---------- epilogue: emb_sel & final ----------
  {
    const int g = tid >> 5, cc = tid & 31;
    float p = 0.f;
    const int n0 = g * 32;
    for (int nn = 0; nn < 32; ++nn) {
      const int n = n0 + nn;
      p += sm[OFF_UNITS + n] * sm[OFF_KEY + cc * KROW + n];
    }
    if (g == 15) p += sm[OFF_UNITS + N_] * sm[OFF_KEY + cc * KROW + N_];
    sm[OFF_PART + g * 32 + cc] = p;
  }
  for (int n = tid; n < NP_; n += 512) out_units[(size_t)b * NP_ + n] = sm[OFF_UNITS + n];
  __syncthreads();
  if (tid < 32) {
    float s = 0.f;
    #pragma unroll
    for (int g = 0; g < 16; ++g) s += sm[OFF_PART + g * 32 + tid];
    sm[OFF_ES + tid] = s / 513.0f;
  }
  __syncthreads();
  {
    const float* e = emb + (size_t)b * 1024;
    for (int d = tid; d < 1024; d += 512) {
      float a = 0.f;
      #pragma unroll
      for (int k = 0; k < 32; ++k) a += sm[OFF_ES + k] * emb_w[k * 1024 + d];
      out_final[(size_t)b * 1024 + d] = e[d] + a + emb_b[d];
    }
  }
}

extern "C" void kernel_launch(void* const* d_in, const int* in_sizes, int n_in,
                              void* d_out, int out_size, void* d_ws, size_t ws_size,
                              hipStream_t stream) {
  (void)in_sizes; (void)n_in; (void)ws_size; (void)out_size;
  const float* emb    = (const float*)d_in[0];
  const float* autm   = (const float*)d_in[1];
  const float* aum    = (const float*)d_in[2];
  const float* ent    = (const float*)d_in[3];
  const float* temp   = (const float*)d_in[4];
  const float* key_w  = (const float*)d_in[5];
  const float* key_b  = (const float*)d_in[6];
  const float* func_w = (const float*)d_in[7];
  const float* func_b = (const float*)d_in[8];
  const float* fc1_w  = (const float*)d_in[9];
  const float* fc1_b  = (const float*)d_in[10];
  const float* fc2_w  = (const float*)d_in[11];
  const float* fc2_b  = (const float*)d_in[12];
  const float* emb_w  = (const float*)d_in[13];
  const float* emb_b  = (const float*)d_in[14];
  const float* wx     = (const float*)d_in[15];
  const float* wh     = (const float*)d_in[16];
  const float* lb     = (const float*)d_in[17];
  const float* gxg    = (const float*)d_in[18];
  const float* gxb    = (const float*)d_in[19];
  const float* ghg    = (const float*)d_in[20];
  const float* ghb    = (const float*)d_in[21];
  float* out = (float*)d_out;
  float* ws  = (float*)d_ws;

  // output layout: logits[64,256,513] | valid[64,256] | units[256,513] | final[256,1024]
  const size_t OFF_V = (size_t)T_ * B_ * NP_;
  const size_t OFF_U = OFF_V + (size_t)T_ * B_;
  const size_t OFF_F = OFF_U + (size_t)B_ * NP_;

  SkKeys sk = compute_chain();

  pre_kernel<<<dim3(1280), dim3(256), 0, stream>>>(
      ent, key_w, key_b, emb, fc1_w, fc1_b, autm, func_w, func_b,
      fc2_w, fc2_b, ws);

  suh_kernel<<<dim3(B_), dim3(512), LDS_FLOATS * sizeof(float), stream>>>(
      ws, aum, temp, emb, emb_w, emb_b,
      wx, wh, lb, gxg, gxb, ghg, ghb,
      out, out + OFF_V, out + OFF_U, out + OFF_F, sk);
}

// Round 5
// 275.440 us; speedup vs baseline: 1.8005x; 1.0920x over previous
//
#include <hip/hip_runtime.h>
#include <stdint.h>
#include <stddef.h>

// ==== JAX threefry mode: 1 = jax_threefry_partitionable (default in modern JAX)
#define JAX_PARTITIONABLE 1

#define B_   256
#define N_   512
#define NP_  513     // N+1
#define KROW 516     // padded key row stride (floats), 16B-aligned
#define T_   64
#define CS   4       // sampling chunk size (steps)
#define NCH  16      // T_/CS
#define NEGC 1e9f

// ---------------- threefry2x32 (matches jax/_src/prng.py) ----------------
__host__ __device__ __forceinline__ void tf2x32(uint32_t k0, uint32_t k1,
    uint32_t x0, uint32_t x1, uint32_t& o0, uint32_t& o1) {
  const uint32_t k2 = k0 ^ k1 ^ 0x1BD11BDAu;
#define TFR(r) { x0 += x1; x1 = (x1 << (r)) | (x1 >> (32 - (r))); x1 ^= x0; }
  x0 += k0; x1 += k1;
  TFR(13) TFR(15) TFR(26) TFR(6)
  x0 += k1; x1 += k2 + 1u;
  TFR(17) TFR(29) TFR(16) TFR(24)
  x0 += k2; x1 += k0 + 2u;
  TFR(13) TFR(15) TFR(26) TFR(6)
  x0 += k0; x1 += k1 + 3u;
  TFR(17) TFR(29) TFR(16) TFR(24)
  x0 += k1; x1 += k2 + 4u;
  TFR(13) TFR(15) TFR(26) TFR(6)
  x0 += k2; x1 += k0 + 5u;
#undef TFR
  o0 = x0; o1 = x1;
}

struct SkKeys { uint32_t k[128]; };

static SkKeys compute_chain() {
  SkKeys s;
  uint32_t r0 = 0u, r1 = 42u;   // jax.random.key(42)
  for (int t = 0; t < 64; ++t) {
#if JAX_PARTITIONABLE
    uint32_t a0, a1, b0, b1;
    tf2x32(r0, r1, 0u, 0u, a0, a1);
    tf2x32(r0, r1, 0u, 1u, b0, b1);
    s.k[2*t] = b0; s.k[2*t+1] = b1;
    r0 = a0; r1 = a1;
#else
    uint32_t p0, p1, q0, q1;
    tf2x32(r0, r1, 0u, 2u, p0, p1);
    tf2x32(r0, r1, 1u, 3u, q0, q1);
    s.k[2*t] = p1; s.k[2*t+1] = q1;
    r0 = p0; r1 = q0;
#endif
  }
  return s;
}

__device__ __forceinline__ float gumbel_draw(uint32_t k0, uint32_t k1, int b, int n) {
  uint32_t bits;
#if JAX_PARTITIONABLE
  uint32_t j = (uint32_t)(b * NP_ + n);
  uint32_t o0, o1; tf2x32(k0, k1, 0u, j, o0, o1);
  bits = o0 ^ o1;
#else
  int j = b * NP_ + n;
  uint32_t o0, o1;
  if (j < 65664) { tf2x32(k0, k1, (uint32_t)j, (uint32_t)(j + 65664), o0, o1); bits = o0; }
  else           { tf2x32(k0, k1, (uint32_t)(j - 65664), (uint32_t)j, o0, o1); bits = o1; }
#endif
  float f = __uint_as_float((bits >> 9) | 0x3F800000u) - 1.0f;
  const float TINY = 1.17549435e-38f;
  float u = fmaxf(TINY, f + TINY);
  return -logf(-logf(u));
}

__device__ __forceinline__ float sigm(float x) {
  return 0.5f + 0.5f * tanhf(0.5f * x);   // XLA logistic
}

// barrier with LDS-only drain (no vmcnt: global stores never read back)
__device__ __forceinline__ void bar_lds() {
  asm volatile("s_waitcnt lgkmcnt(0)\n\ts_barrier" ::: "memory");
}

// ---------------- workspace layout (floats) ----------------
#define WS_KEY 0                       // [B][32][KROW] c-major
#define WS_X0  (B_ * 32 * KROW)        // [B][32]

// =============== kernel 1: key GEMM (blocks 0..1023) + x0 MLP (1024..1279) ===============
__global__ void __launch_bounds__(256)
pre_kernel(const float* __restrict__ ent, const float* __restrict__ key_w,
           const float* __restrict__ key_b,
           const float* __restrict__ emb, const float* __restrict__ fc1_w,
           const float* __restrict__ fc1_b,
           const float* __restrict__ autm, const float* __restrict__ func_w,
           const float* __restrict__ func_b,
           const float* __restrict__ fc2_w, const float* __restrict__ fc2_b,
           float* __restrict__ ws)
{
  __shared__ __align__(16) float smAll[16384];
  const int tid = threadIdx.x;

  if (blockIdx.x < 1024) {
    float* smA = smAll;            // [64][128] k-major
    float* smW = smAll + 8192;     // [256][32]
    const int blk = blockIdx.x;
    const int R0  = blk * 128;
    const int b   = R0 >> 9;
    const int nb  = R0 & 511;
    const int rg  = tid >> 3;
    const int cg  = tid & 7;

    for (int i = tid; i < 2048; i += 256)
      ((float4*)smW)[i] = ((const float4*)key_w)[i];

    float acc[4][4];
    #pragma unroll
    for (int i = 0; i < 4; ++i)
      #pragma unroll
      for (int j = 0; j < 4; ++j) acc[i][j] = 0.f;

    const int row  = tid >> 1;
    const int half = tid & 1;

    for (int kc = 0; kc < 4; ++kc) {
      const float4* src = (const float4*)(ent + ((size_t)(R0 + row)) * 256 + kc * 64 + half * 32);
      float4 vv[8];
      #pragma unroll
      for (int r = 0; r < 8; ++r) vv[r] = src[r];
      #pragma unroll
      for (int r = 0; r < 8; ++r) {
        const int kl = half * 32 + r * 4;
        smA[(kl + 0) * 128 + row] = vv[r].x;
        smA[(kl + 1) * 128 + row] = vv[r].y;
        smA[(kl + 2) * 128 + row] = vv[r].z;
        smA[(kl + 3) * 128 + row] = vv[r].w;
      }
      __syncthreads();
      #pragma unroll 4
      for (int k = 0; k < 64; ++k) {
        float4 av = *(const float4*)&smA[k * 128 + rg * 4];
        float4 bv = *(const float4*)&smW[(kc * 64 + k) * 32 + cg * 4];
        float ar[4] = {av.x, av.y, av.z, av.w};
        float br[4] = {bv.x, bv.y, bv.z, bv.w};
        #pragma unroll
        for (int i = 0; i < 4; ++i)
          #pragma unroll
          for (int j = 0; j < 4; ++j) acc[i][j] += ar[i] * br[j];
      }
      __syncthreads();
    }
    float4 bb = *(const float4*)&key_b[cg * 4];
    float bbr[4] = {bb.x, bb.y, bb.z, bb.w};
    #pragma unroll
    for (int j = 0; j < 4; ++j) {
      const int c = cg * 4 + j;
      float* dst = ws + WS_KEY + ((size_t)(b * 32 + c)) * KROW + nb + rg * 4;
      #pragma unroll
      for (int i = 0; i < 4; ++i) dst[i] = acc[i][j] + bbr[j];
    }
  } else {
    float* smX = smAll;
    const int b = blockIdx.x - 1024;
    const int j = tid;
    {
      float a = 0.f;
      const float* e = emb + (size_t)b * 1024;
      #pragma unroll 8
      for (int k = 0; k < 1024; ++k) a += e[k] * fc1_w[k * 256 + j];
      a = fmaxf(a + fc1_b[j], 0.f);
      float f = 0.f;
      const float* m = autm + (size_t)b * 259;
      for (int k = 0; k < 259; ++k) f += m[k] * func_w[k * 256 + j];
      f = fmaxf(f + func_b[j], 0.f);
      smX[j] = a + f;
    }
    __syncthreads();
    if (j < 32) {
      float s = 0.f;
      #pragma unroll 8
      for (int m = 0; m < 256; ++m) s += smX[m] * fc2_w[m * 32 + j];
      ws[WS_X0 + b * 32 + j] = fmaxf(s + fc2_b[j], 0.f);
    }
  }
}

// =============== kernel 2: scan ===============
// LDS layout (floats)
#define OFF_KEY   0        // 32*516 = 16512, c-major [32][516]
#define OFF_H     16512    // 64*32 = 2048
#define OFF_Q     18560    // 2*CS*516 = 4128
#define OFF_G     22688    // 4128
#define OFF_UNITS 26816    // 513 (pad 516)
#define OFF_SK    27332    // 128 (u32 aliased)
#define OFF_ES    27460    // 32
#define OFF_PART  27492    // 512
#define LDS_FLOATS 28004   // 112,016 B

__global__ void __launch_bounds__(512, 2)
suh_kernel(const float* __restrict__ ws_key_x0,
           const float* __restrict__ aum, const float* __restrict__ temp_p,
           const float* __restrict__ emb,
           const float* __restrict__ emb_w, const float* __restrict__ emb_b,
           const float* __restrict__ wx, const float* __restrict__ wh,
           const float* __restrict__ lstm_bb,
           const float* __restrict__ ln_gx, const float* __restrict__ ln_bx,
           const float* __restrict__ ln_gh, const float* __restrict__ ln_bh,
           float* __restrict__ out_logits, float* __restrict__ out_valid,
           float* __restrict__ out_units, float* __restrict__ out_final,
           SkKeys sk)
{
  extern __shared__ __align__(16) float sm[];
  int* smi = (int*)sm;
  const int b   = blockIdx.x;
  const int tid = threadIdx.x;

  // ---------- prologue: key -> LDS, sk chain -> LDS ----------
  {
    const float4* kv = (const float4*)(ws_key_x0 + WS_KEY + (size_t)b * (32 * KROW));
    for (int i = tid; i < (32 * KROW) / 4; i += 512) ((float4*)sm)[i] = kv[i];
  }
  if (tid < 128) smi[OFF_SK + tid] = (int)sk.k[tid];
  __syncthreads();
  if (tid < 32) sm[OFF_KEY + tid * KROW + N_] = 0.f;   // appended zero key row
  // (ordered for waves 1-7 by the beta barrier below; wave0 writes it itself)

  const float temp = temp_p[0];

  // wave0-persistent sampling state
  float mreg[8], ureg[8];
  float m512 = 1.0f;
  int done_reg = 0;

  // ---------- beta: wave0 runs all 64 LSTM steps, no barriers ----------
  if (tid < 64) {
    float wxr0[32], wxr1[32], whr0[32], whr1[32];
    #pragma unroll
    for (int k = 0; k < 32; ++k) {
      wxr0[k] = wx[k * 128 + tid];
      wxr1[k] = wx[k * 128 + 64 + tid];
      whr0[k] = wh[k * 128 + tid];
      whr1[k] = wh[k * 128 + 64 + tid];
    }
    const float gxg0 = ln_gx[tid], gxg1 = ln_gx[tid + 64];
    const float gxb0 = ln_bx[tid], gxb1 = ln_bx[tid + 64];
    const float ghg0 = ln_gh[tid], ghg1 = ln_gh[tid + 64];
    const float ghb0 = ln_bh[tid], ghb1 = ln_bh[tid + 64];
    const float lb0  = lstm_bb[tid], lb1 = lstm_bb[tid + 64];

    float xfrag[32];
    {
      const float* x0g = ws_key_x0 + WS_X0 + b * 32;
      #pragma unroll
      for (int r = 0; r < 8; ++r) {
        float4 v = *(const float4*)(x0g + r * 4);
        xfrag[r*4] = v.x; xfrag[r*4+1] = v.y; xfrag[r*4+2] = v.z; xfrag[r*4+3] = v.w;
      }
    }
    float creg = 0.f;

    #pragma unroll 1
    for (int t = 0; t < T_; ++t) {
      float a0 = 0.f, a1 = 0.f, b0 = 0.f, b1 = 0.f;
      #pragma unroll
      for (int k = 0; k < 32; ++k) {
        a0 += xfrag[k] * wxr0[k];
        a1 += xfrag[k] * wxr1[k];
      }
      if (t > 0) {                       // at t==0, h==0 -> gh exactly 0
        #pragma unroll
        for (int k = 0; k < 32; ++k) {
          b0 += xfrag[k] * whr0[k];
          b1 += xfrag[k] * whr1[k];
        }
      }
      // interleaved LN butterflies (identical op order to the passing kernel)
      float sx = a0 + a1, sh = b0 + b1;
      for (int off = 32; off; off >>= 1) {
        sx += __shfl_down(sx, off);
        sh += __shfl_down(sh, off);
      }
      float mx  = __shfl(sx, 0) * (1.0f / 128.0f);
      float mhh = __shfl(sh, 0) * (1.0f / 128.0f);
      float dx0 = a0 - mx, dx1 = a1 - mx;
      float dh0 = b0 - mhh, dh1 = b1 - mhh;
      float ssx = dx0 * dx0 + dx1 * dx1;
      float ssh = dh0 * dh0 + dh1 * dh1;
      for (int off = 32; off; off >>= 1) {
        ssx += __shfl_down(ssx, off);
        ssh += __shfl_down(ssh, off);
      }
      float vx = __shfl(ssx, 0) * (1.0f / 128.0f);
      float vh = __shfl(ssh, 0) * (1.0f / 128.0f);
      float rx = 1.0f / sqrtf(vx + 1e-5f);
      float rh = 1.0f / sqrtf(vh + 1e-5f);
      float lnx0 = dx0 * rx * gxg0 + gxb0;
      float lnx1 = dx1 * rx * gxg1 + gxb1;
      float lnh0 = dh0 * rh * ghg0 + ghb0;
      float lnh1 = dh1 * rh * ghg1 + ghb1;
      float g0 = lnx0 + lnh0 + lb0;      // gate[tid]     (i|f half)
      float g1 = lnx1 + lnh1 + lb1;      // gate[tid+64]  (o|u half)
      float fq = __shfl(g0, tid + 32);
      float uq = __shfl(g1, tid + 32);
      if (tid < 32) {
        float cN = sigm(fq) * creg + sigm(g0) * tanhf(uq);
        float hN = sigm(g1) * tanhf(cN);
        creg = cN;
        sm[OFF_H + t * 32 + tid] = hN;
      }
      // broadcast h_t to all 64 lanes for the next step
      #pragma unroll
      for (int r = 0; r < 8; ++r) {
        float4 v = *(const float4*)&sm[OFF_H + t * 32 + r * 4];
        xfrag[r*4] = v.x; xfrag[r*4+1] = v.y; xfrag[r*4+2] = v.z; xfrag[r*4+3] = v.w;
      }
    }
  }
  __syncthreads();   // beta done: H complete, key zero-row visible everywhere

  // ---------- chunk prep (waves 1-7): Q[CS][513] + GUM[CS][513] ----------
  auto do_prep = [&](int cc, int pbuf) {
    const int L = tid - 64;                     // 0..447
    const int qb = OFF_Q + pbuf * (CS * 516);
    const int gb = OFF_G + pbuf * (CS * 516);
    // Q: lane handles n = L (and n = 448+L for L < 65)
    #pragma unroll 1
    for (int pass = 0; pass < 2; ++pass) {
      const int n = L + pass * 448;
      if (pass == 0 || L < 65) {
        float kreg[32];
        #pragma unroll
        for (int k = 0; k < 32; ++k) kreg[k] = sm[OFF_KEY + k * KROW + n];
        #pragma unroll
        for (int tl = 0; tl < CS; ++tl) {
          float acc = 0.f;
          #pragma unroll
          for (int k = 0; k < 32; ++k) acc += sm[OFF_H + (cc * CS + tl) * 32 + k] * kreg[k];
          sm[qb + tl * 516 + n] = acc * (1.0f / 32.0f);
        }
      }
    }
    // gumbels: CS x 512 grid + CS extras for n=512
    #pragma unroll 1
    for (int i = 0; i < (CS * 512 + 447) / 448; ++i) {
      const int idx = i * 448 + L;
      if (idx < CS * 512) {
        const int tl = idx >> 9;
        const int n  = idx & 511;
        const int t  = cc * CS + tl;
        sm[gb + tl * 516 + n] =
            gumbel_draw((uint32_t)smi[OFF_SK + 2*t], (uint32_t)smi[OFF_SK + 2*t + 1], b, n);
      }
    }
    if (L < CS) {
      const int t = cc * CS + L;
      sm[gb + L * 516 + N_] =
          gumbel_draw((uint32_t)smi[OFF_SK + 2*t], (uint32_t)smi[OFF_SK + 2*t + 1], b, N_);
    }
  };

  if (tid >= 64) {
    do_prep(0, 0);
  } else {
    // wave0: load sampling state
    #pragma unroll
    for (int j = 0; j < 8; ++j) {
      const int n = tid + 64 * j;            // <= 511
      mreg[j] = aum[(size_t)b * N_ + n];
      ureg[j] = 0.f;
    }
  }
  bar_lds();

  // ---------- pipelined sampling: wave0 samples chunk c, waves 1-7 prep c+1 ----------
  for (int c = 0; c < NCH; ++c) {
    const int pb = c & 1;
    if (tid < 64) {
      const int qbase = OFF_Q + pb * (CS * 516);
      const int gbase = OFF_G + pb * (CS * 516);
      #pragma unroll 1
      for (int tl = 0; tl < CS; ++tl) {
        const int t = c * CS + tl;
        float* lrow = out_logits + ((size_t)t * B_ + b) * NP_;
        float bv = 0.f; int bi = 0;
        #pragma unroll
        for (int j = 0; j < 8; ++j) {
          const int n = tid + 64 * j;
          float q = sm[qbase + tl * 516 + n] - (1.0f - mreg[j]) * NEGC;
          lrow[n] = q;
          float v = q / temp + sm[gbase + tl * 516 + n];
          if (j == 0) { bv = v; bi = n; }
          else if (v > bv) { bv = v; bi = n; }
        }
        if (tid == 0) {
          float q = -(1.0f - m512) * NEGC;   // zero key row: dot == 0
          lrow[N_] = q;
          float v = q / temp + sm[gbase + tl * 516 + N_];
          if (v > bv) { bv = v; bi = N_; }
        }
        for (int off = 32; off; off >>= 1) {
          float ov = __shfl_down(bv, off);
          int   oi = __shfl_down(bi, off);
          if (ov > bv || (ov == bv && oi < bi)) { bv = ov; bi = oi; }
        }
        const int sel_i = __shfl(bi, 0);
        const int active = !done_reg;
        const int is_end = (sel_i == N_);
        if (tid == 0) out_valid[(size_t)t * B_ + b] = active ? 1.0f : 0.0f;
        if (active && !is_end) {
          #pragma unroll
          for (int j = 0; j < 8; ++j)
            if (tid + 64 * j == sel_i) { mreg[j] = 0.0f; ureg[j] = 1.0f; }
        }
        if (active && is_end) done_reg = 1;
      }
    } else if (c + 1 < NCH) {
      do_prep(c + 1, (c + 1) & 1);
    }
    bar_lds();
  }

  // wave0 publishes units
  if (tid < 64) {
    #pragma unroll
    for (int j = 0; j < 8; ++j) sm[OFF_UNITS + tid + 64 * j] = ureg[j];
    if (tid == 0) sm[OFF_UNITS + N_] = 0.f;
  }
  __syncthreads();

  // ---------- epilogue: emb_sel & final ----------
  {
    const int g = tid >> 5, cc = tid & 31;
    float p = 0.f;
    const int n0 = g * 32;
    for (int nn = 0; nn < 32; ++nn) {
      const int n = n0 + nn;
      p += sm[OFF_UNITS + n] * sm[OFF_KEY + cc * KROW + n];
    }
    if (g == 15) p += sm[OFF_UNITS + N_] * sm[OFF_KEY + cc * KROW + N_];
    sm[OFF_PART + g * 32 + cc] = p;
  }
  for (int n = tid; n < NP_; n += 512) out_units[(size_t)b * NP_ + n] = sm[OFF_UNITS + n];
  __syncthreads();
  if (tid < 32) {
    float s = 0.f;
    #pragma unroll
    for (int g = 0; g < 16; ++g) s += sm[OFF_PART + g * 32 + tid];
    sm[OFF_ES + tid] = s / 513.0f;
  }
  __syncthreads();
  {
    const float* e = emb + (size_t)b * 1024;
    for (int d = tid; d < 1024; d += 512) {
      float a = 0.f;
      #pragma unroll
      for (int k = 0; k < 32; ++k) a += sm[OFF_ES + k] * emb_w[k * 1024 + d];
      out_final[(size_t)b * 1024 + d] = e[d] + a + emb_b[d];
    }
  }
}

extern "C" void kernel_launch(void* const* d_in, const int* in_sizes, int n_in,
                              void* d_out, int out_size, void* d_ws, size_t ws_size,
                              hipStream_t stream) {
  (void)in_sizes; (void)n_in; (void)ws_size; (void)out_size;
  const float* emb    = (const float*)d_in[0];
  const float* autm   = (const float*)d_in[1];
  const float* aum    = (const float*)d_in[2];
  const float* ent    = (const float*)d_in[3];
  const float* temp   = (const float*)d_in[4];
  const float* key_w  = (const float*)d_in[5];
  const float* key_b  = (const float*)d_in[6];
  const float* func_w = (const float*)d_in[7];
  const float* func_b = (const float*)d_in[8];
  const float* fc1_w  = (const float*)d_in[9];
  const float* fc1_b  = (const float*)d_in[10];
  const float* fc2_w  = (const float*)d_in[11];
  const float* fc2_b  = (const float*)d_in[12];
  const float* emb_w  = (const float*)d_in[13];
  const float* emb_b  = (const float*)d_in[14];
  const float* wx     = (const float*)d_in[15];
  const float* wh     = (const float*)d_in[16];
  const float* lb     = (const float*)d_in[17];
  const float* gxg    = (const float*)d_in[18];
  const float* gxb    = (const float*)d_in[19];
  const float* ghg    = (const float*)d_in[20];
  const float* ghb    = (const float*)d_in[21];
  float* out = (float*)d_out;
  float* ws  = (float*)d_ws;

  // output layout: logits[64,256,513] | valid[64,256] | units[256,513] | final[256,1024]
  const size_t OFF_V = (size_t)T_ * B_ * NP_;
  const size_t OFF_U = OFF_V + (size_t)T_ * B_;
  const size_t OFF_F = OFF_U + (size_t)B_ * NP_;

  SkKeys sk = compute_chain();

  pre_kernel<<<dim3(1280), dim3(256), 0, stream>>>(
      ent, key_w, key_b, emb, fc1_w, fc1_b, autm, func_w, func_b,
      fc2_w, fc2_b, ws);

  suh_kernel<<<dim3(B_), dim3(512), LDS_FLOATS * sizeof(float), stream>>>(
      ws, aum, temp, emb, emb_w, emb_b,
      wx, wh, lb, gxg, gxb, ghg, ghb,
      out, out + OFF_V, out + OFF_U, out + OFF_F, sk);
}

// Round 6
// 242.380 us; speedup vs baseline: 2.0461x; 1.1364x over previous
//
#include <hip/hip_runtime.h>
#include <stdint.h>
#include <stddef.h>

// ==== JAX threefry mode: 1 = jax_threefry_partitionable (default in modern JAX)
#define JAX_PARTITIONABLE 1

#define B_   256
#define N_   512
#define NP_  513     // N+1
#define KROW 516     // padded key row stride (floats), 16B-aligned
#define T_   64
#define CS   4       // sampling chunk size (steps)
#define NCH  16      // T_/CS
#define NEGC 1e9f

// ---------------- threefry2x32 (matches jax/_src/prng.py) ----------------
__host__ __device__ __forceinline__ void tf2x32(uint32_t k0, uint32_t k1,
    uint32_t x0, uint32_t x1, uint32_t& o0, uint32_t& o1) {
  const uint32_t k2 = k0 ^ k1 ^ 0x1BD11BDAu;
#define TFR(r) { x0 += x1; x1 = (x1 << (r)) | (x1 >> (32 - (r))); x1 ^= x0; }
  x0 += k0; x1 += k1;
  TFR(13) TFR(15) TFR(26) TFR(6)
  x0 += k1; x1 += k2 + 1u;
  TFR(17) TFR(29) TFR(16) TFR(24)
  x0 += k2; x1 += k0 + 2u;
  TFR(13) TFR(15) TFR(26) TFR(6)
  x0 += k0; x1 += k1 + 3u;
  TFR(17) TFR(29) TFR(16) TFR(24)
  x0 += k1; x1 += k2 + 4u;
  TFR(13) TFR(15) TFR(26) TFR(6)
  x0 += k2; x1 += k0 + 5u;
#undef TFR
  o0 = x0; o1 = x1;
}

struct SkKeys { uint32_t k[128]; };

static SkKeys compute_chain() {
  SkKeys s;
  uint32_t r0 = 0u, r1 = 42u;   // jax.random.key(42)
  for (int t = 0; t < 64; ++t) {
#if JAX_PARTITIONABLE
    uint32_t a0, a1, b0, b1;
    tf2x32(r0, r1, 0u, 0u, a0, a1);
    tf2x32(r0, r1, 0u, 1u, b0, b1);
    s.k[2*t] = b0; s.k[2*t+1] = b1;
    r0 = a0; r1 = a1;
#else
    uint32_t p0, p1, q0, q1;
    tf2x32(r0, r1, 0u, 2u, p0, p1);
    tf2x32(r0, r1, 1u, 3u, q0, q1);
    s.k[2*t] = p1; s.k[2*t+1] = q1;
    r0 = p0; r1 = q0;
#endif
  }
  return s;
}

__device__ __forceinline__ float gumbel_draw(uint32_t k0, uint32_t k1, int b, int n) {
  uint32_t bits;
#if JAX_PARTITIONABLE
  uint32_t j = (uint32_t)(b * NP_ + n);
  uint32_t o0, o1; tf2x32(k0, k1, 0u, j, o0, o1);
  bits = o0 ^ o1;
#else
  int j = b * NP_ + n;
  uint32_t o0, o1;
  if (j < 65664) { tf2x32(k0, k1, (uint32_t)j, (uint32_t)(j + 65664), o0, o1); bits = o0; }
  else           { tf2x32(k0, k1, (uint32_t)(j - 65664), (uint32_t)j, o0, o1); bits = o1; }
#endif
  float f = __uint_as_float((bits >> 9) | 0x3F800000u) - 1.0f;
  const float TINY = 1.17549435e-38f;
  float u = fmaxf(TINY, f + TINY);
  return -logf(-logf(u));
}

__device__ __forceinline__ float sigm(float x) {
  return 0.5f + 0.5f * tanhf(0.5f * x);   // XLA logistic
}

// barrier with LDS-only drain (no vmcnt: global stores never read back)
__device__ __forceinline__ void bar_lds() {
  asm volatile("s_waitcnt lgkmcnt(0)\n\ts_barrier" ::: "memory");
}

// ---------------- LDS layout (floats) ----------------
#define OFF_KEY   0        // 32*516 = 16512, c-major [32][516]
#define OFF_H     16512    // 64*32 = 2048
#define OFF_Q     18560    // 2 slots * 4*516 = 4128
#define OFF_G     22688    // 5 slots * 4*516 = 10320
#define OFF_UNITS 33008    // 516
#define OFF_SK    33524    // 128 (u32 aliased)
#define OFF_ES    33652    // 32
#define OFF_PART  33684    // 512
#define OFF_T     34196    // 256
#define OFF_X0    34452    // 32
#define LDS_FLOATS 34484   // 137,936 B

__global__ void __launch_bounds__(512, 2)
suh_fused(const float* __restrict__ emb, const float* __restrict__ autm,
          const float* __restrict__ aum, const float* __restrict__ ent,
          const float* __restrict__ temp_p,
          const float* __restrict__ key_w, const float* __restrict__ key_b,
          const float* __restrict__ func_w, const float* __restrict__ func_b,
          const float* __restrict__ fc1_w, const float* __restrict__ fc1_b,
          const float* __restrict__ fc2_w, const float* __restrict__ fc2_b,
          const float* __restrict__ emb_w, const float* __restrict__ emb_b,
          const float* __restrict__ wx, const float* __restrict__ wh,
          const float* __restrict__ lstm_bb,
          const float* __restrict__ ln_gx, const float* __restrict__ ln_bx,
          const float* __restrict__ ln_gh, const float* __restrict__ ln_bh,
          float* __restrict__ out_logits, float* __restrict__ out_valid,
          float* __restrict__ out_units, float* __restrict__ out_final,
          SkKeys sk)
{
  extern __shared__ __align__(16) float sm[];
  int* smi = (int*)sm;
  const int b   = blockIdx.x;
  const int tid = threadIdx.x;
  const int L   = tid - 64;         // worker lane id (valid for tid >= 64)

  const float temp = temp_p[0];

  // ======== P0: T = relu(emb@fc1+b1) + relu(autm@func+fb)  (identical chains to pre) ========
  if (tid < 256) {
    float a = 0.f;
    const float* e = emb + (size_t)b * 1024;
    #pragma unroll 8
    for (int k = 0; k < 1024; ++k) a += e[k] * fc1_w[k * 256 + tid];
    a = fmaxf(a + fc1_b[tid], 0.f);
    float f = 0.f;
    const float* m = autm + (size_t)b * 259;
    for (int k = 0; k < 259; ++k) f += m[k] * func_w[k * 256 + tid];
    f = fmaxf(f + func_b[tid], 0.f);
    sm[OFF_T + tid] = a + f;
  } else {
    if (tid < 384) smi[OFF_SK + (tid - 256)] = (int)sk.k[tid - 256];
    if (tid >= 480) sm[OFF_KEY + (tid - 480) * KROW + N_] = 0.f;  // zero key row
  }
  __syncthreads();

  // ======== P1: x0 = relu(T@fc2 + b2) ========
  if (tid < 32) {
    float s = 0.f;
    #pragma unroll 8
    for (int m2 = 0; m2 < 256; ++m2) s += sm[OFF_T + m2] * fc2_w[m2 * 32 + tid];
    sm[OFF_X0 + tid] = fmaxf(s + fc2_b[tid], 0.f);
  }
  __syncthreads();

  // persistent worker state (key columns in registers)
  float kr0[32], kr1[32];
  // persistent wave0 sampling state
  float mreg[8], ureg[8];
  float m512 = 1.0f;
  int done_reg = 0;

  // prep lambdas (workers)
  auto qprep = [&](int cc, int qs) {
    const int qb = OFF_Q + qs * (CS * 516);
    #pragma unroll 1
    for (int tl = 0; tl < CS; ++tl) {
      const int hb = OFF_H + (cc * CS + tl) * 32;
      float hv[32];
      #pragma unroll
      for (int r = 0; r < 8; ++r) {
        float4 v = *(const float4*)&sm[hb + r * 4];
        hv[r*4] = v.x; hv[r*4+1] = v.y; hv[r*4+2] = v.z; hv[r*4+3] = v.w;
      }
      float a0 = 0.f;
      #pragma unroll
      for (int k = 0; k < 32; ++k) a0 += hv[k] * kr0[k];
      sm[qb + tl * 516 + L] = a0 * (1.0f / 32.0f);
      if (L < 64) {
        float a1 = 0.f;
        #pragma unroll
        for (int k = 0; k < 32; ++k) a1 += hv[k] * kr1[k];
        sm[qb + tl * 516 + L + 448] = a1 * (1.0f / 32.0f);
      }
    }
  };
  auto gprep = [&](int cc, int gs) {
    const int gb = OFF_G + gs * (CS * 516);
    #pragma unroll 1
    for (int i = 0; i < 5; ++i) {                 // ceil(CS*512/448)
      const int idx = i * 448 + L;
      if (idx < CS * 512) {
        const int tl = idx >> 9, n = idx & 511;
        const int t = cc * CS + tl;
        sm[gb + tl * 516 + n] =
            gumbel_draw((uint32_t)smi[OFF_SK + 2*t], (uint32_t)smi[OFF_SK + 2*t + 1], b, n);
      }
    }
    if (L < CS) {
      const int t = cc * CS + L;
      sm[gb + L * 516 + N_] =
          gumbel_draw((uint32_t)smi[OFF_SK + 2*t], (uint32_t)smi[OFF_SK + 2*t + 1], b, N_);
    }
  };

  // ======== P2: wave0 beta (64 LSTM steps) || workers key GEMM + gumbel prefill ========
  if (tid < 64) {
    // ---- persistent weights in VGPRs (pinned) ----
    float wxr0[32], wxr1[32], whr0[32], whr1[32];
    #pragma unroll
    for (int k = 0; k < 32; ++k) {
      wxr0[k] = wx[k * 128 + tid];
      wxr1[k] = wx[k * 128 + 64 + tid];
      whr0[k] = wh[k * 128 + tid];
      whr1[k] = wh[k * 128 + 64 + tid];
    }
    #pragma unroll
    for (int k = 0; k < 32; ++k) {
      asm volatile("" : "+v"(wxr0[k]), "+v"(wxr1[k]), "+v"(whr0[k]), "+v"(whr1[k]));
    }
    const float gxg0 = ln_gx[tid], gxg1 = ln_gx[tid + 64];
    const float gxb0 = ln_bx[tid], gxb1 = ln_bx[tid + 64];
    const float ghg0 = ln_gh[tid], ghg1 = ln_gh[tid + 64];
    const float ghb0 = ln_bh[tid], ghb1 = ln_bh[tid + 64];
    const float lb0  = lstm_bb[tid], lb1 = lstm_bb[tid + 64];

    float xf[32];
    #pragma unroll
    for (int r = 0; r < 8; ++r) {
      float4 v = *(const float4*)&sm[OFF_X0 + r * 4];
      xf[r*4] = v.x; xf[r*4+1] = v.y; xf[r*4+2] = v.z; xf[r*4+3] = v.w;
    }
    float creg = 0.f;

    #pragma unroll 1
    for (int t = 0; t < T_; ++t) {
      float a0 = 0.f, a1 = 0.f, b0 = 0.f, b1 = 0.f;
      #pragma unroll
      for (int k = 0; k < 32; ++k) { a0 += xf[k] * wxr0[k]; a1 += xf[k] * wxr1[k]; }
      if (t > 0) {                        // at t==0, h==0 -> gh exactly 0
        #pragma unroll
        for (int k = 0; k < 32; ++k) { b0 += xf[k] * whr0[k]; b1 += xf[k] * whr1[k]; }
      }
      float sx = a0 + a1, sh = b0 + b1;
      for (int off = 32; off; off >>= 1) {
        sx += __shfl_down(sx, off);
        sh += __shfl_down(sh, off);
      }
      float mx  = __shfl(sx, 0) * (1.0f / 128.0f);
      float mh2 = __shfl(sh, 0) * (1.0f / 128.0f);
      float dx0 = a0 - mx, dx1 = a1 - mx;
      float dh0 = b0 - mh2, dh1 = b1 - mh2;
      float ssx = dx0 * dx0 + dx1 * dx1;
      float ssh = dh0 * dh0 + dh1 * dh1;
      for (int off = 32; off; off >>= 1) {
        ssx += __shfl_down(ssx, off);
        ssh += __shfl_down(ssh, off);
      }
      float vx = __shfl(ssx, 0) * (1.0f / 128.0f);
      float vh = __shfl(ssh, 0) * (1.0f / 128.0f);
      float rx = 1.0f / sqrtf(vx + 1e-5f);
      float rh = 1.0f / sqrtf(vh + 1e-5f);
      float lnx0 = dx0 * rx * gxg0 + gxb0;
      float lnx1 = dx1 * rx * gxg1 + gxb1;
      float lnh0 = dh0 * rh * ghg0 + ghb0;
      float lnh1 = dh1 * rh * ghg1 + ghb1;
      float g0 = lnx0 + lnh0 + lb0;       // gate[tid]     (i|f half)
      float g1 = lnx1 + lnh1 + lb1;       // gate[tid+64]  (o|u half)
      float fq = __shfl(g0, tid + 32);
      float uq = __shfl(g1, tid + 32);
      float cN = sigm(fq) * creg + sigm(g0) * tanhf(uq);
      float hN = sigm(g1) * tanhf(cN);
      creg = cN;                           // garbage in lanes>=32, never read
      if (tid < 32) sm[OFF_H + t * 32 + tid] = hN;
      #pragma unroll
      for (int k = 0; k < 32; ++k) xf[k] = __shfl(hN, k);   // h broadcast, no LDS read
    }
  } else {
    // ---- workers: key GEMM rows n = L (and L+448 for L<64), ascending-k chains ----
    const float4* kw4 = (const float4*)key_w;
    {
      const float4* er = (const float4*)(ent + ((size_t)b * N_ + L) * 256);
      float acc[32];
      #pragma unroll
      for (int c = 0; c < 32; ++c) acc[c] = 0.f;
      #pragma unroll 1
      for (int k4 = 0; k4 < 64; ++k4) {
        float4 ev = er[k4];
        float e4[4] = {ev.x, ev.y, ev.z, ev.w};
        #pragma unroll
        for (int j = 0; j < 4; ++j) {
          const int k = k4 * 4 + j;
          #pragma unroll
          for (int c4 = 0; c4 < 8; ++c4) {
            float4 w = kw4[k * 8 + c4];          // wave-uniform -> s_load
            acc[c4*4+0] += e4[j] * w.x;
            acc[c4*4+1] += e4[j] * w.y;
            acc[c4*4+2] += e4[j] * w.z;
            acc[c4*4+3] += e4[j] * w.w;
          }
        }
      }
      #pragma unroll
      for (int c = 0; c < 32; ++c) {
        kr0[c] = acc[c] + key_b[c];
        sm[OFF_KEY + c * KROW + L] = kr0[c];
      }
    }
    if (L < 64) {
      const int n = L + 448;
      const float4* er = (const float4*)(ent + ((size_t)b * N_ + n) * 256);
      float acc[32];
      #pragma unroll
      for (int c = 0; c < 32; ++c) acc[c] = 0.f;
      #pragma unroll 1
      for (int k4 = 0; k4 < 64; ++k4) {
        float4 ev = er[k4];
        float e4[4] = {ev.x, ev.y, ev.z, ev.w};
        #pragma unroll
        for (int j = 0; j < 4; ++j) {
          const int k = k4 * 4 + j;
          #pragma unroll
          for (int c4 = 0; c4 < 8; ++c4) {
            float4 w = kw4[k * 8 + c4];
            acc[c4*4+0] += e4[j] * w.x;
            acc[c4*4+1] += e4[j] * w.y;
            acc[c4*4+2] += e4[j] * w.z;
            acc[c4*4+3] += e4[j] * w.w;
          }
        }
      }
      #pragma unroll
      for (int c = 0; c < 32; ++c) {
        kr1[c] = acc[c] + key_b[c];
        sm[OFF_KEY + c * KROW + n] = kr1[c];
      }
    }
    #pragma unroll
    for (int k = 0; k < 32; ++k) {
      asm volatile("" : "+v"(kr0[k]), "+v"(kr1[k]));
    }
    // gumbel prefill for chunks 0..3 (G ring slots 0..3) — hidden under beta
    #pragma unroll 1
    for (int cc = 0; cc < 4; ++cc) gprep(cc, cc);
  }
  __syncthreads();   // H + key + G[0..3] complete

  // ======== P3 pre-loop: workers prep Q(0); wave0 loads mask state ========
  if (tid < 64) {
    #pragma unroll
    for (int j = 0; j < 8; ++j) {
      mreg[j] = aum[(size_t)b * N_ + tid + 64 * j];
      ureg[j] = 0.f;
    }
  } else {
    qprep(0, 0);
  }
  bar_lds();

  // ======== pipelined sampling: wave0 samples chunk c || workers prep Q(c+1), G(c+4) ========
  for (int c = 0; c < NCH; ++c) {
    if (tid < 64) {
      const int qbase = OFF_Q + (c & 1) * (CS * 516);
      const int gbase = OFF_G + (c % 5) * (CS * 516);
      #pragma unroll 1
      for (int tl = 0; tl < CS; ++tl) {
        const int t = c * CS + tl;
        float* lrow = out_logits + ((size_t)t * B_ + b) * NP_;
        float bv = 0.f; int bi = 0;
        #pragma unroll
        for (int j = 0; j < 8; ++j) {
          const int n = tid + 64 * j;
          float q = sm[qbase + tl * 516 + n] - (1.0f - mreg[j]) * NEGC;
          lrow[n] = q;
          float v = q / temp + sm[gbase + tl * 516 + n];
          if (j == 0) { bv = v; bi = n; }
          else if (v > bv) { bv = v; bi = n; }
        }
        if (tid == 0) {
          float q = -(1.0f - m512) * NEGC;   // zero key row: dot == 0
          lrow[N_] = q;
          float v = q / temp + sm[gbase + tl * 516 + N_];
          if (v > bv) { bv = v; bi = N_; }
        }
        for (int off = 32; off; off >>= 1) {
          float ov = __shfl_down(bv, off);
          int   oi = __shfl_down(bi, off);
          if (ov > bv || (ov == bv && oi < bi)) { bv = ov; bi = oi; }
        }
        const int sel_i = __shfl(bi, 0);
        const int active = !done_reg;
        const int is_end = (sel_i == N_);
        if (tid == 0) out_valid[(size_t)t * B_ + b] = active ? 1.0f : 0.0f;
        if (active && !is_end) {
          #pragma unroll
          for (int j = 0; j < 8; ++j)
            if (tid + 64 * j == sel_i) { mreg[j] = 0.0f; ureg[j] = 1.0f; }
        }
        if (active && is_end) done_reg = 1;
      }
    } else {
      if (c + 1 < NCH) qprep(c + 1, (c + 1) & 1);
      if (c + 4 < NCH) gprep(c + 4, (c + 4) % 5);
    }
    bar_lds();
  }

  // wave0 publishes units
  if (tid < 64) {
    #pragma unroll
    for (int j = 0; j < 8; ++j) sm[OFF_UNITS + tid + 64 * j] = ureg[j];
    if (tid == 0) sm[OFF_UNITS + N_] = 0.f;
  }
  __syncthreads();

  // ======== epilogue: emb_sel & final ========
  {
    const int g = tid >> 5, cc = tid & 31;
    float p = 0.f;
    const int n0 = g * 32;
    for (int nn = 0; nn < 32; ++nn) {
      const int n = n0 + nn;
      p += sm[OFF_UNITS + n] * sm[OFF_KEY + cc * KROW + n];
    }
    if (g == 15) p += sm[OFF_UNITS + N_] * sm[OFF_KEY + cc * KROW + N_];
    sm[OFF_PART + g * 32 + cc] = p;
  }
  for (int n = tid; n < NP_; n += 512) out_units[(size_t)b * NP_ + n] = sm[OFF_UNITS + n];
  __syncthreads();
  if (tid < 32) {
    float s = 0.f;
    #pragma unroll
    for (int g = 0; g < 16; ++g) s += sm[OFF_PART + g * 32 + tid];
    sm[OFF_ES + tid] = s / 513.0f;
  }
  __syncthreads();
  {
    const float* e = emb + (size_t)b * 1024;
    for (int d = tid; d < 1024; d += 512) {
      float a = 0.f;
      #pragma unroll
      for (int k = 0; k < 32; ++k) a += sm[OFF_ES + k] * emb_w[k * 1024 + d];
      out_final[(size_t)b * 1024 + d] = e[d] + a + emb_b[d];
    }
  }
}

extern "C" void kernel_launch(void* const* d_in, const int* in_sizes, int n_in,
                              void* d_out, int out_size, void* d_ws, size_t ws_size,
                              hipStream_t stream) {
  (void)in_sizes; (void)n_in; (void)d_ws; (void)ws_size; (void)out_size;
  const float* emb    = (const float*)d_in[0];
  const float* autm   = (const float*)d_in[1];
  const float* aum    = (const float*)d_in[2];
  const float* ent    = (const float*)d_in[3];
  const float* temp   = (const float*)d_in[4];
  const float* key_w  = (const float*)d_in[5];
  const float* key_b  = (const float*)d_in[6];
  const float* func_w = (const float*)d_in[7];
  const float* func_b = (const float*)d_in[8];
  const float* fc1_w  = (const float*)d_in[9];
  const float* fc1_b  = (const float*)d_in[10];
  const float* fc2_w  = (const float*)d_in[11];
  const float* fc2_b  = (const float*)d_in[12];
  const float* emb_w  = (const float*)d_in[13];
  const float* emb_b  = (const float*)d_in[14];
  const float* wx     = (const float*)d_in[15];
  const float* wh     = (const float*)d_in[16];
  const float* lb     = (const float*)d_in[17];
  const float* gxg    = (const float*)d_in[18];
  const float* gxb    = (const float*)d_in[19];
  const float* ghg    = (const float*)d_in[20];
  const float* ghb    = (const float*)d_in[21];
  float* out = (float*)d_out;

  // output layout: logits[64,256,513] | valid[64,256] | units[256,513] | final[256,1024]
  const size_t OFF_V = (size_t)T_ * B_ * NP_;
  const size_t OFF_U = OFF_V + (size_t)T_ * B_;
  const size_t OFF_F = OFF_U + (size_t)B_ * NP_;

  SkKeys sk = compute_chain();

  suh_fused<<<dim3(B_), dim3(512), LDS_FLOATS * sizeof(float), stream>>>(
      emb, autm, aum, ent, temp, key_w, key_b, func_w, func_b,
      fc1_w, fc1_b, fc2_w, fc2_b, emb_w, emb_b,
      wx, wh, lb, gxg, gxb, ghg, ghb,
      out, out + OFF_V, out + OFF_U, out + OFF_F, sk);
}